// Round 1
// baseline (2536.710 us; speedup 1.0000x reference)
//
#include <hip/hip_runtime.h>
#include <cmath>

#define D_MODEL 512
#define S_LEN   900
#define BATCH   16
#define NHEADS  8
#define MTOT    (BATCH * S_LEN)   // 14400

// output layout (floats)
#define OFF_ROT   7372800
#define OFF_REFL  7372864
#define OFF_TRANS 7372992
#define OFF_SCAL  7373024
#define OFF_TP    7373072

typedef float  f32x4  __attribute__((ext_vector_type(4)));
typedef short  short8 __attribute__((ext_vector_type(8)));

__device__ __forceinline__ short f2bf(float f) {
    unsigned u = __builtin_bit_cast(unsigned, f);
    unsigned r = (u + 0x7fffu + ((u >> 16) & 1u)) >> 16;
    return (short)r;
}

__device__ __forceinline__ float gelu_f(float x) {
    return 0.5f * x * (1.0f + erff(x * 0.70710678118654752440f));
}

// ---------------------------------------------------------------------------
// Generic GEMM: C[M,N] = epilogue(A[M,K] @ W[N,K]^T + bias)
// bf16 MFMA 16x16x32, 128x128 tile, BK=32, 4 waves (2x2), reg-staged LDS.
// mode 0: plain (+bias); 1: gelu; 2: C = res + 0.3*(acc+bias)
// ---------------------------------------------------------------------------
__global__ __launch_bounds__(256) void gemm_kernel(
    const float* __restrict__ A, const float* __restrict__ W,
    const float* __restrict__ bias, const float* __restrict__ res,
    float* __restrict__ C, int Mr, int N, int K, int mode) {
    __shared__ short As[128 * 40];
    __shared__ short Bs[128 * 40];
    const int t    = threadIdx.x;
    const int bn   = blockIdx.x, bm = blockIdx.y;
    const int row  = t >> 1;
    const int koff = (t & 1) * 16;
    const int wid  = t >> 6, lane = t & 63;
    const int wm   = wid >> 1, wn = wid & 1;
    const int lr   = lane & 15;
    const int ko8  = (lane >> 4) * 8;
    const bool k4  = (K & 3) == 0;
    const int arow = bm * 128 + row;
    const int wrow = bn * 128 + row;
    const int nk   = (K + 31) / 32;

    f32x4 acc[4][4] = {};

    for (int kt = 0; kt < nk; ++kt) {
        const int k0 = kt * 32;
        // ---- stage A tile ----
        float va[16];
        if (k4 && arow < Mr && (k0 + koff + 16) <= K) {
            const float4* p = (const float4*)(A + (size_t)arow * K + k0 + koff);
            float4 x0 = p[0], x1 = p[1], x2 = p[2], x3 = p[3];
            va[0]=x0.x; va[1]=x0.y; va[2]=x0.z; va[3]=x0.w;
            va[4]=x1.x; va[5]=x1.y; va[6]=x1.z; va[7]=x1.w;
            va[8]=x2.x; va[9]=x2.y; va[10]=x2.z; va[11]=x2.w;
            va[12]=x3.x; va[13]=x3.y; va[14]=x3.z; va[15]=x3.w;
        } else {
            #pragma unroll
            for (int j = 0; j < 16; ++j) {
                int kk = k0 + koff + j;
                va[j] = (arow < Mr && kk < K) ? A[(size_t)arow * K + kk] : 0.f;
            }
        }
        // ---- stage W tile ----
        float vb[16];
        if (k4 && (k0 + koff + 16) <= K) {
            const float4* p = (const float4*)(W + (size_t)wrow * K + k0 + koff);
            float4 x0 = p[0], x1 = p[1], x2 = p[2], x3 = p[3];
            vb[0]=x0.x; vb[1]=x0.y; vb[2]=x0.z; vb[3]=x0.w;
            vb[4]=x1.x; vb[5]=x1.y; vb[6]=x1.z; vb[7]=x1.w;
            vb[8]=x2.x; vb[9]=x2.y; vb[10]=x2.z; vb[11]=x2.w;
            vb[12]=x3.x; vb[13]=x3.y; vb[14]=x3.z; vb[15]=x3.w;
        } else {
            #pragma unroll
            for (int j = 0; j < 16; ++j) {
                int kk = k0 + koff + j;
                vb[j] = (kk < K) ? W[(size_t)wrow * K + kk] : 0.f;
            }
        }
        short8 sa0, sa1, sb0, sb1;
        #pragma unroll
        for (int j = 0; j < 8; ++j) {
            sa0[j] = f2bf(va[j]);  sa1[j] = f2bf(va[8 + j]);
            sb0[j] = f2bf(vb[j]);  sb1[j] = f2bf(vb[8 + j]);
        }
        *(short8*)&As[row * 40 + koff]     = sa0;
        *(short8*)&As[row * 40 + koff + 8] = sa1;
        *(short8*)&Bs[row * 40 + koff]     = sb0;
        *(short8*)&Bs[row * 40 + koff + 8] = sb1;
        __syncthreads();

        short8 af[4], bf[4];
        #pragma unroll
        for (int m = 0; m < 4; ++m)
            af[m] = *(const short8*)&As[(wm * 64 + m * 16 + lr) * 40 + ko8];
        #pragma unroll
        for (int n = 0; n < 4; ++n)
            bf[n] = *(const short8*)&Bs[(wn * 64 + n * 16 + lr) * 40 + ko8];
        #pragma unroll
        for (int m = 0; m < 4; ++m)
            #pragma unroll
            for (int n = 0; n < 4; ++n)
                acc[m][n] = __builtin_amdgcn_mfma_f32_16x16x32_bf16(af[m], bf[n], acc[m][n], 0, 0, 0);
        __syncthreads();
    }

    // ---- epilogue ----
    #pragma unroll
    for (int m = 0; m < 4; ++m) {
        int grow_base = bm * 128 + wm * 64 + m * 16 + (lane >> 4) * 4;
        #pragma unroll
        for (int j = 0; j < 4; ++j) {
            int grow = grow_base + j;
            if (grow >= Mr) continue;
            #pragma unroll
            for (int n = 0; n < 4; ++n) {
                int gcol = bn * 128 + wn * 64 + n * 16 + lr;
                float v = acc[m][n][j] + bias[gcol];
                if (mode == 1) v = gelu_f(v);
                else if (mode == 2) v = res[(size_t)grow * N + gcol] + 0.3f * v;
                C[(size_t)grow * N + gcol] = v;
            }
        }
    }
}

// ---------------------------------------------------------------------------
// geo bias: bg[h][q][k] = dist_emb[dist,h] + dir_emb[dir,h]
// ---------------------------------------------------------------------------
__global__ void geo_bias_kernel(const float* __restrict__ dist_emb,
                                const float* __restrict__ dir_emb,
                                float* __restrict__ bg) {
    int idx = blockIdx.x * 256 + threadIdx.x;
    if (idx >= S_LEN * S_LEN) return;
    int q = idx / S_LEN, k = idx % S_LEN;
    int h1 = q / 30, w1 = q % 30;
    int h2 = k / 30, w2 = k % 30;
    int dh = h2 - h1, dw = w2 - w1;
    int dist = min((int)floorf(sqrtf((float)(dh * dh + dw * dw))), 59);
    int dir = 0;
    if (dh != 0 || dw != 0) {
        const float PI_F = 3.14159265358979323846f;
        float ang = atan2f((float)dh, (float)dw);
        dir = ((int)floorf((ang + PI_F) / (PI_F * 0.25f))) & 7;
    }
    #pragma unroll
    for (int hd = 0; hd < 8; ++hd)
        bg[((size_t)hd * S_LEN + q) * S_LEN + k] = dist_emb[dist * 8 + hd] + dir_emb[dir * 8 + hd];
}

// ---------------------------------------------------------------------------
// fused attention: per (b,h,q-tile of 16): scores in LDS, softmax, PV
// q,k,v layout: [B,S,512] with col = h*64+d. bg: [8,900,900].
// ---------------------------------------------------------------------------
__global__ __launch_bounds__(256) void attn_kernel(
    const float* __restrict__ qp, const float* __restrict__ kp,
    const float* __restrict__ vp, const float* __restrict__ bg,
    float* __restrict__ op) {
    __shared__ float sc[16][900];
    __shared__ float qld[16][68];
    __shared__ float kv[64][68];
    const int t = threadIdx.x;
    const int w = t >> 6, lane = t & 63;
    const int bh = blockIdx.y, b = bh >> 3, h = bh & 7;
    const int q0 = blockIdx.x * 16;

    for (int idx = t; idx < 16 * 64; idx += 256) {
        int r = idx >> 6, d = idx & 63;
        int qs = q0 + r;
        qld[r][d] = (qs < S_LEN) ? qp[((size_t)(b * S_LEN + qs)) * D_MODEL + h * 64 + d] * 0.125f : 0.f;
    }
    const float* bgh = bg + (size_t)h * S_LEN * S_LEN;
    const int tq = t & 3, tk = t >> 2;

    for (int k0 = 0; k0 < S_LEN; k0 += 64) {
        int kn = min(64, S_LEN - k0);
        __syncthreads();
        for (int idx = t; idx < kn * 64; idx += 256) {
            int r = idx >> 6, d = idx & 63;
            kv[r][d] = kp[((size_t)(b * S_LEN + k0 + r)) * D_MODEL + h * 64 + d];
        }
        __syncthreads();
        if (tk < kn) {
            float a0 = 0, a1 = 0, a2 = 0, a3 = 0;
            #pragma unroll 8
            for (int d = 0; d < 64; ++d) {
                float kvv = kv[tk][d];
                a0 += qld[tq * 4 + 0][d] * kvv;
                a1 += qld[tq * 4 + 1][d] * kvv;
                a2 += qld[tq * 4 + 2][d] * kvv;
                a3 += qld[tq * 4 + 3][d] * kvv;
            }
            int kk = k0 + tk;
            int qa = q0 + tq * 4;
            sc[tq * 4 + 0][kk] = a0 + ((qa + 0 < S_LEN) ? bgh[(size_t)(qa + 0) * S_LEN + kk] : 0.f);
            sc[tq * 4 + 1][kk] = a1 + ((qa + 1 < S_LEN) ? bgh[(size_t)(qa + 1) * S_LEN + kk] : 0.f);
            sc[tq * 4 + 2][kk] = a2 + ((qa + 2 < S_LEN) ? bgh[(size_t)(qa + 2) * S_LEN + kk] : 0.f);
            sc[tq * 4 + 3][kk] = a3 + ((qa + 3 < S_LEN) ? bgh[(size_t)(qa + 3) * S_LEN + kk] : 0.f);
        }
    }
    __syncthreads();
    // softmax: wave w handles rows w, w+4, w+8, w+12
    for (int r = w; r < 16; r += 4) {
        float m = -1e30f;
        for (int k = lane; k < S_LEN; k += 64) m = fmaxf(m, sc[r][k]);
        #pragma unroll
        for (int off = 32; off >= 1; off >>= 1) m = fmaxf(m, __shfl_xor(m, off));
        float ssum = 0.f;
        for (int k = lane; k < S_LEN; k += 64) {
            float e = expf(sc[r][k] - m);
            sc[r][k] = e;
            ssum += e;
        }
        #pragma unroll
        for (int off = 32; off >= 1; off >>= 1) ssum += __shfl_xor(ssum, off);
        float inv = 1.f / ssum;
        for (int k = lane; k < S_LEN; k += 64) sc[r][k] *= inv;
    }
    // PV: thread owns rows {w,4+w,8+w,12+w} at col d=lane
    float acc0 = 0, acc1 = 0, acc2 = 0, acc3 = 0;
    for (int k0 = 0; k0 < S_LEN; k0 += 64) {
        int kn = min(64, S_LEN - k0);
        __syncthreads();
        for (int idx = t; idx < kn * 64; idx += 256) {
            int r = idx >> 6, d = idx & 63;
            kv[r][d] = vp[((size_t)(b * S_LEN + k0 + r)) * D_MODEL + h * 64 + d];
        }
        __syncthreads();
        for (int kk = 0; kk < kn; ++kk) {
            float vv = kv[kk][lane];
            acc0 += sc[0 + w][k0 + kk] * vv;
            acc1 += sc[4 + w][k0 + kk] * vv;
            acc2 += sc[8 + w][k0 + kk] * vv;
            acc3 += sc[12 + w][k0 + kk] * vv;
        }
    }
    int qs;
    qs = q0 + 0 + w;  if (qs < S_LEN) op[((size_t)(b * S_LEN + qs)) * D_MODEL + h * 64 + lane] = acc0;
    qs = q0 + 4 + w;  if (qs < S_LEN) op[((size_t)(b * S_LEN + qs)) * D_MODEL + h * 64 + lane] = acc1;
    qs = q0 + 8 + w;  if (qs < S_LEN) op[((size_t)(b * S_LEN + qs)) * D_MODEL + h * 64 + lane] = acc2;
    qs = q0 + 12 + w; if (qs < S_LEN) op[((size_t)(b * S_LEN + qs)) * D_MODEL + h * 64 + lane] = acc3;
}

// ---------------------------------------------------------------------------
// LN: out[row] = LN(src[row] + res[row]) * g + b   (512 cols, wave per row)
// ---------------------------------------------------------------------------
__global__ __launch_bounds__(256) void ln_kernel(
    const float* __restrict__ src, const float* __restrict__ res,
    const float* __restrict__ g, const float* __restrict__ bb,
    float* __restrict__ out) {
    int row = blockIdx.x * 4 + (threadIdx.x >> 6);
    int lane = threadIdx.x & 63;
    const float* s = src + (size_t)row * D_MODEL;
    const float* r = res + (size_t)row * D_MODEL;
    float v[8];
    float tot = 0.f;
    #pragma unroll
    for (int i = 0; i < 8; ++i) {
        int c = lane * 8 + i;
        v[i] = s[c] + r[c];
        tot += v[i];
    }
    #pragma unroll
    for (int off = 32; off >= 1; off >>= 1) tot += __shfl_xor(tot, off);
    float mean = tot * (1.f / 512.f);
    float var = 0.f;
    #pragma unroll
    for (int i = 0; i < 8; ++i) { v[i] -= mean; var += v[i] * v[i]; }
    #pragma unroll
    for (int off = 32; off >= 1; off >>= 1) var += __shfl_xor(var, off);
    float rstd = rsqrtf(var * (1.f / 512.f) + 1e-5f);
    float* o = out + (size_t)row * D_MODEL;
    #pragma unroll
    for (int i = 0; i < 8; ++i) {
        int c = lane * 8 + i;
        o[c] = v[i] * rstd * g[c] + bb[c];
    }
}

__global__ void mean_part_kernel(const float* __restrict__ attn_out, float* __restrict__ partial) {
    int b = blockIdx.x, chunk = blockIdx.y, t = threadIdx.x;
    int s0 = chunk * 100;
    for (int c = t; c < 512; c += 256) {
        float s = 0.f;
        for (int i = 0; i < 100; ++i)
            s += attn_out[((size_t)(b * S_LEN + s0 + i)) * D_MODEL + c];
        partial[((size_t)(b * 9 + chunk)) * 512 + c] = s;
    }
}

__global__ void mean_final_kernel(const float* __restrict__ partial, float* __restrict__ gfeat) {
    int idx = blockIdx.x * 256 + threadIdx.x;
    if (idx >= 16 * 512) return;
    int b = idx / 512, c = idx % 512;
    float s = 0.f;
    for (int i = 0; i < 9; ++i) s += partial[((size_t)(b * 9 + i)) * 512 + c];
    gfeat[idx] = s * (1.0f / 900.0f);
}

__global__ void heads_kernel(const float* __restrict__ gfeat,
    const float* __restrict__ rot_w, const float* __restrict__ rot_b,
    const float* __restrict__ refl_w, const float* __restrict__ refl_b,
    const float* __restrict__ trans_w, const float* __restrict__ trans_b,
    const float* __restrict__ scale_w, const float* __restrict__ scale_b,
    float* __restrict__ dout, float* __restrict__ tp_ws) {
    int b = blockIdx.x, t = threadIdx.x;
    __shared__ float hv[17], tpl[17];
    if (t < 17) {
        const float* wrow; float bb;
        if (t < 4)       { wrow = rot_w + t * 512;          bb = rot_b[t]; }
        else if (t < 12) { wrow = refl_w + (t - 4) * 512;   bb = refl_b[t - 4]; }
        else if (t < 14) { wrow = trans_w + (t - 12) * 512; bb = trans_b[t - 12]; }
        else             { wrow = scale_w + (t - 14) * 512; bb = scale_b[t - 14]; }
        const float* gf = gfeat + b * 512;
        float s = bb;
        for (int i = 0; i < 512; ++i) s += gf[i] * wrow[i];
        if (t == 12 || t == 13) s = tanhf(s);
        hv[t] = s;
    }
    __syncthreads();
    if (t == 0) {
        for (int gidx = 0; gidx < 3; ++gidx) {
            int o = (gidx == 0) ? 0 : (gidx == 1) ? 4 : 14;
            int n = (gidx == 0) ? 4 : (gidx == 1) ? 8 : 3;
            float m = hv[o];
            for (int i = 1; i < n; ++i) m = fmaxf(m, hv[o + i]);
            float sum = 0.f;
            for (int i = 0; i < n; ++i) { float e = expf(hv[o + i] - m); tpl[o + i] = e; sum += e; }
            float inv = 1.f / sum;
            for (int i = 0; i < n; ++i) tpl[o + i] *= inv;
        }
        tpl[12] = hv[12];
        tpl[13] = hv[13];
    }
    __syncthreads();
    if (t < 4)  dout[OFF_ROT + b * 4 + t] = hv[t];
    if (t < 8)  dout[OFF_REFL + b * 8 + t] = hv[4 + t];
    if (t < 2)  dout[OFF_TRANS + b * 2 + t] = hv[12 + t];
    if (t < 3)  dout[OFF_SCAL + b * 3 + t] = hv[14 + t];
    if (t < 17) { dout[OFF_TP + b * 17 + t] = tpl[t]; tp_ws[b * 17 + t] = tpl[t]; }
}

__global__ void ti_kernel(const float* __restrict__ attn_out, const float* __restrict__ tp,
                          float* __restrict__ ti) {
    long idx = (long)blockIdx.x * 256 + threadIdx.x;
    if (idx >= (long)MTOT * 529) return;
    int r = (int)(idx / 529), c = (int)(idx % 529);
    float v;
    if (c < 512) v = attn_out[(size_t)r * 512 + c];
    else         v = tp[(r / S_LEN) * 17 + (c - 512)];
    ti[idx] = v;
}

// ---------------------------------------------------------------------------
extern "C" void kernel_launch(void* const* d_in, const int* in_sizes, int n_in,
                              void* d_out, int out_size, void* d_ws, size_t ws_size,
                              hipStream_t stream) {
    const float* x       = (const float*)d_in[0];
    const float* wq      = (const float*)d_in[1];  const float* bq      = (const float*)d_in[2];
    const float* wk      = (const float*)d_in[3];  const float* bk      = (const float*)d_in[4];
    const float* wv      = (const float*)d_in[5];  const float* bv      = (const float*)d_in[6];
    const float* wo      = (const float*)d_in[7];  const float* bo      = (const float*)d_in[8];
    const float* ln_a_g  = (const float*)d_in[9];  const float* ln_a_b  = (const float*)d_in[10];
    const float* dist_e  = (const float*)d_in[11]; const float* dir_e   = (const float*)d_in[12];
    const float* rot_w   = (const float*)d_in[13]; const float* rot_b   = (const float*)d_in[14];
    const float* refl_w  = (const float*)d_in[15]; const float* refl_b  = (const float*)d_in[16];
    const float* trans_w = (const float*)d_in[17]; const float* trans_b = (const float*)d_in[18];
    const float* scale_w = (const float*)d_in[19]; const float* scale_b = (const float*)d_in[20];
    const float* tn1_w   = (const float*)d_in[21]; const float* tn1_b   = (const float*)d_in[22];
    const float* tn2_w   = (const float*)d_in[23]; const float* tn2_b   = (const float*)d_in[24];
    const float* tn3_w   = (const float*)d_in[25]; const float* tn3_b   = (const float*)d_in[26];
    const float* ff1_w   = (const float*)d_in[27]; const float* ff1_b   = (const float*)d_in[28];
    const float* ff2_w   = (const float*)d_in[29]; const float* ff2_b   = (const float*)d_in[30];
    const float* ln2_g   = (const float*)d_in[31]; const float* ln2_b   = (const float*)d_in[32];
    float* out = (float*)d_out;
    float* ws  = (float*)d_ws;

    // ws layout (floats), lifetime-overlapped; total 58,416,592 f (223 MiB)
    float* bufA   = ws + 0;         // q, later T1 (wo out)          7372800
    float* bufB   = ws + 7372800;   // k, later attn_out             7372800
    float* bufC   = ws + 14745600;  // v, later h2                   7372800
    float* bufE   = ws + 22118400;  // geo bias                      6480000
    float* bufF   = ws + 28598400;  // ti                            7617600
    float* bufG   = ws + 36216000;  // h1, later ffo                14745600
    float* bufD   = ws + 50961600;  // attnv, later geo              7372800
    float* gfeat  = ws + 58334400;  // 8192
    float* partial= ws + 58342592;  // 73728
    float* tpbuf  = ws + 58416320;  // 272
    float* ffh    = ws + 0;         // [M,2048] overlaps dead A,B,C,E,F

    dim3 blk(256);
    geo_bias_kernel<<<dim3((S_LEN * S_LEN + 255) / 256), blk, 0, stream>>>(dist_e, dir_e, bufE);
    gemm_kernel<<<dim3(4, 113), blk, 0, stream>>>(x, wq, bq, nullptr, bufA, MTOT, 512, 512, 0);
    gemm_kernel<<<dim3(4, 113), blk, 0, stream>>>(x, wk, bk, nullptr, bufB, MTOT, 512, 512, 0);
    gemm_kernel<<<dim3(4, 113), blk, 0, stream>>>(x, wv, bv, nullptr, bufC, MTOT, 512, 512, 0);
    attn_kernel<<<dim3(57, 128), blk, 0, stream>>>(bufA, bufB, bufC, bufE, bufD);
    gemm_kernel<<<dim3(4, 113), blk, 0, stream>>>(bufD, wo, bo, nullptr, bufA, MTOT, 512, 512, 0);
    ln_kernel<<<3600, blk, 0, stream>>>(bufA, x, ln_a_g, ln_a_b, bufB);          // attn_out
    mean_part_kernel<<<dim3(16, 9), blk, 0, stream>>>(bufB, partial);
    mean_final_kernel<<<32, blk, 0, stream>>>(partial, gfeat);
    heads_kernel<<<16, 64, 0, stream>>>(gfeat, rot_w, rot_b, refl_w, refl_b,
                                        trans_w, trans_b, scale_w, scale_b, out, tpbuf);
    ti_kernel<<<(int)(((long)MTOT * 529 + 255) / 256), blk, 0, stream>>>(bufB, tpbuf, bufF);
    gemm_kernel<<<dim3(8, 113), blk, 0, stream>>>(bufF, tn1_w, tn1_b, nullptr, bufG, MTOT, 1024, 529, 1);
    gemm_kernel<<<dim3(4, 113), blk, 0, stream>>>(bufG, tn2_w, tn2_b, nullptr, bufC, MTOT, 512, 1024, 1);
    gemm_kernel<<<dim3(4, 113), blk, 0, stream>>>(bufC, tn3_w, tn3_b, bufB, bufD, MTOT, 512, 512, 2); // geo
    gemm_kernel<<<dim3(16, 113), blk, 0, stream>>>(bufD, ff1_w, ff1_b, nullptr, ffh, MTOT, 2048, 512, 1);
    gemm_kernel<<<dim3(4, 113), blk, 0, stream>>>(ffh, ff2_w, ff2_b, nullptr, bufG, MTOT, 512, 2048, 0);
    ln_kernel<<<3600, blk, 0, stream>>>(bufG, bufD, ln2_g, ln2_b, out);
}

// Round 2
// 1727.255 us; speedup vs baseline: 1.4686x; 1.4686x over previous
//
#include <hip/hip_runtime.h>
#include <cmath>

#define D_MODEL 512
#define S_LEN   900
#define BATCH   16
#define NHEADS  8
#define MTOT    (BATCH * S_LEN)   // 14400

// output layout (floats)
#define OFF_ROT   7372800
#define OFF_REFL  7372864
#define OFF_TRANS 7372992
#define OFF_SCAL  7373024
#define OFF_TP    7373072

typedef float  f32x4   __attribute__((ext_vector_type(4)));
typedef short  short8  __attribute__((ext_vector_type(8)));
typedef short  short4v __attribute__((ext_vector_type(4)));

__device__ __forceinline__ short f2bf(float f) {
    unsigned u = __builtin_bit_cast(unsigned, f);
    unsigned r = (u + 0x7fffu + ((u >> 16) & 1u)) >> 16;
    return (short)r;
}
__device__ __forceinline__ float bf2f(short s) {
    unsigned u = ((unsigned)(unsigned short)s) << 16;
    return __builtin_bit_cast(float, u);
}

__device__ __forceinline__ float gelu_f(float x) {
    return 0.5f * x * (1.0f + erff(x * 0.70710678118654752440f));
}

// ---------------------------------------------------------------------------
// Generic GEMM: C[M,N] = epilogue(A[M,K] @ W[N,K]^T + bias)
// bf16 MFMA 16x16x32, 128x128 tile, BK=32, 4 waves (2x2), reg-staged LDS.
// mode 0: plain (+bias); 1: gelu; 2: C = res + 0.3*(acc+bias)
// ---------------------------------------------------------------------------
__global__ __launch_bounds__(256) void gemm_kernel(
    const float* __restrict__ A, const float* __restrict__ W,
    const float* __restrict__ bias, const float* __restrict__ res,
    float* __restrict__ C, int Mr, int N, int K, int mode) {
    __shared__ short As[128 * 40];
    __shared__ short Bs[128 * 40];
    const int t    = threadIdx.x;
    const int bn   = blockIdx.x, bm = blockIdx.y;
    const int row  = t >> 1;
    const int koff = (t & 1) * 16;
    const int wid  = t >> 6, lane = t & 63;
    const int wm   = wid >> 1, wn = wid & 1;
    const int lr   = lane & 15;
    const int ko8  = (lane >> 4) * 8;
    const bool k4  = (K & 3) == 0;
    const int arow = bm * 128 + row;
    const int wrow = bn * 128 + row;
    const int nk   = (K + 31) / 32;

    f32x4 acc[4][4] = {};

    for (int kt = 0; kt < nk; ++kt) {
        const int k0 = kt * 32;
        float va[16];
        if (k4 && arow < Mr && (k0 + koff + 16) <= K) {
            const float4* p = (const float4*)(A + (size_t)arow * K + k0 + koff);
            float4 x0 = p[0], x1 = p[1], x2 = p[2], x3 = p[3];
            va[0]=x0.x; va[1]=x0.y; va[2]=x0.z; va[3]=x0.w;
            va[4]=x1.x; va[5]=x1.y; va[6]=x1.z; va[7]=x1.w;
            va[8]=x2.x; va[9]=x2.y; va[10]=x2.z; va[11]=x2.w;
            va[12]=x3.x; va[13]=x3.y; va[14]=x3.z; va[15]=x3.w;
        } else {
            #pragma unroll
            for (int j = 0; j < 16; ++j) {
                int kk = k0 + koff + j;
                va[j] = (arow < Mr && kk < K) ? A[(size_t)arow * K + kk] : 0.f;
            }
        }
        float vb[16];
        if (k4 && (k0 + koff + 16) <= K) {
            const float4* p = (const float4*)(W + (size_t)wrow * K + k0 + koff);
            float4 x0 = p[0], x1 = p[1], x2 = p[2], x3 = p[3];
            vb[0]=x0.x; vb[1]=x0.y; vb[2]=x0.z; vb[3]=x0.w;
            vb[4]=x1.x; vb[5]=x1.y; vb[6]=x1.z; vb[7]=x1.w;
            vb[8]=x2.x; vb[9]=x2.y; vb[10]=x2.z; vb[11]=x2.w;
            vb[12]=x3.x; vb[13]=x3.y; vb[14]=x3.z; vb[15]=x3.w;
        } else {
            #pragma unroll
            for (int j = 0; j < 16; ++j) {
                int kk = k0 + koff + j;
                vb[j] = (kk < K) ? W[(size_t)wrow * K + kk] : 0.f;
            }
        }
        short8 sa0, sa1, sb0, sb1;
        #pragma unroll
        for (int j = 0; j < 8; ++j) {
            sa0[j] = f2bf(va[j]);  sa1[j] = f2bf(va[8 + j]);
            sb0[j] = f2bf(vb[j]);  sb1[j] = f2bf(vb[8 + j]);
        }
        *(short8*)&As[row * 40 + koff]     = sa0;
        *(short8*)&As[row * 40 + koff + 8] = sa1;
        *(short8*)&Bs[row * 40 + koff]     = sb0;
        *(short8*)&Bs[row * 40 + koff + 8] = sb1;
        __syncthreads();

        short8 af[4], bf[4];
        #pragma unroll
        for (int m = 0; m < 4; ++m)
            af[m] = *(const short8*)&As[(wm * 64 + m * 16 + lr) * 40 + ko8];
        #pragma unroll
        for (int n = 0; n < 4; ++n)
            bf[n] = *(const short8*)&Bs[(wn * 64 + n * 16 + lr) * 40 + ko8];
        #pragma unroll
        for (int m = 0; m < 4; ++m)
            #pragma unroll
            for (int n = 0; n < 4; ++n)
                acc[m][n] = __builtin_amdgcn_mfma_f32_16x16x32_bf16(af[m], bf[n], acc[m][n], 0, 0, 0);
        __syncthreads();
    }

    #pragma unroll
    for (int m = 0; m < 4; ++m) {
        int grow_base = bm * 128 + wm * 64 + m * 16 + (lane >> 4) * 4;
        #pragma unroll
        for (int j = 0; j < 4; ++j) {
            int grow = grow_base + j;
            if (grow >= Mr) continue;
            #pragma unroll
            for (int n = 0; n < 4; ++n) {
                int gcol = bn * 128 + wn * 64 + n * 16 + lr;
                float v = acc[m][n][j] + bias[gcol];
                if (mode == 1) v = gelu_f(v);
                else if (mode == 2) v = res[(size_t)grow * N + gcol] + 0.3f * v;
                C[(size_t)grow * N + gcol] = v;
            }
        }
    }
}

// ---------------------------------------------------------------------------
// concat wq/wk/wv -> wcat[1536][512], biases -> bcat[1536]
// ---------------------------------------------------------------------------
__global__ void concat_qkv_kernel(
    const float* __restrict__ wq, const float* __restrict__ wk, const float* __restrict__ wv,
    const float* __restrict__ bq, const float* __restrict__ bk, const float* __restrict__ bv,
    float* __restrict__ wcat, float* __restrict__ bcat) {
    int idx = blockIdx.x * 256 + threadIdx.x;
    if (idx < 1536)
        bcat[idx] = (idx < 512) ? bq[idx] : (idx < 1024) ? bk[idx - 512] : bv[idx - 1024];
    if (idx >= 1536 * 512) return;
    int n = idx >> 9, cc = idx & 511;
    const float* src = (n < 512) ? wq : (n < 1024) ? wk : wv;
    wcat[idx] = src[(n & 511) * 512 + cc];
}

// ---------------------------------------------------------------------------
// geo bias
// ---------------------------------------------------------------------------
__global__ void geo_bias_kernel(const float* __restrict__ dist_emb,
                                const float* __restrict__ dir_emb,
                                float* __restrict__ bg) {
    int idx = blockIdx.x * 256 + threadIdx.x;
    if (idx >= S_LEN * S_LEN) return;
    int q = idx / S_LEN, k = idx % S_LEN;
    int h1 = q / 30, w1 = q % 30;
    int h2 = k / 30, w2 = k % 30;
    int dh = h2 - h1, dw = w2 - w1;
    int dist = min((int)floorf(sqrtf((float)(dh * dh + dw * dw))), 59);
    int dir = 0;
    if (dh != 0 || dw != 0) {
        const float PI_F = 3.14159265358979323846f;
        float ang = atan2f((float)dh, (float)dw);
        dir = ((int)floorf((ang + PI_F) / (PI_F * 0.25f))) & 7;
    }
    #pragma unroll
    for (int hd = 0; hd < 8; ++hd)
        bg[((size_t)hd * S_LEN + q) * S_LEN + k] = dist_emb[dist * 8 + hd] + dir_emb[dir * 8 + hd];
}

// ---------------------------------------------------------------------------
// MFMA attention. qkv: [B,S,1536] (q at +0, k at +512, v at +1024).
// Block = (b,h) x 16-q-row tile, 4 waves. Scores/P bf16 in LDS.
// ---------------------------------------------------------------------------
__global__ __launch_bounds__(256) void attn_mfma_kernel(
    const float* __restrict__ qkv, const float* __restrict__ bg,
    float* __restrict__ op) {
    __shared__ short sc[16][928];   // scores then P (bf16)
    __shared__ short qt[16][72];
    __shared__ short kt[64][72];    // K tile row-major; reused as V^T tile
    const int t = threadIdx.x;
    const int w = t >> 6, lane = t & 63;
    const int c = lane & 15, g = lane >> 4;
    const int bh = blockIdx.y, b = bh >> 3, h = bh & 7;
    const int q0 = blockIdx.x * 16;
    const float* qbase = qkv + (size_t)b * S_LEN * 1536 + h * 64;
    const float* kbase = qbase + 512;
    const float* vbase = qbase + 1024;
    const float* bgh   = bg + (size_t)h * S_LEN * S_LEN;

    // stage Q (scaled by 1/sqrt(64))
    {
        int r = t >> 4, c4 = (t & 15) * 4;
        int qs = q0 + r;
        float4 qv = {0.f, 0.f, 0.f, 0.f};
        if (qs < S_LEN) qv = *(const float4*)(qbase + (size_t)qs * 1536 + c4);
        short4v s4;
        s4[0] = f2bf(qv.x * 0.125f); s4[1] = f2bf(qv.y * 0.125f);
        s4[2] = f2bf(qv.z * 0.125f); s4[3] = f2bf(qv.w * 0.125f);
        *(short4v*)&qt[r][c4] = s4;
    }
    __syncthreads();
    short8 qa0 = *(const short8*)&qt[c][g * 8];
    short8 qa1 = *(const short8*)&qt[c][32 + g * 8];

    // ---- QK^T ----
    for (int kt0 = 0; kt0 < S_LEN; kt0 += 64) {
        __syncthreads();
        #pragma unroll
        for (int p = 0; p < 2; ++p) {
            int r  = (t >> 3) + 32 * p;
            int cc = (t & 7) * 8;
            int ks = kt0 + r;
            float4 a = {0.f,0.f,0.f,0.f}, b4 = {0.f,0.f,0.f,0.f};
            if (ks < S_LEN) {
                a  = *(const float4*)(kbase + (size_t)ks * 1536 + cc);
                b4 = *(const float4*)(kbase + (size_t)ks * 1536 + cc + 4);
            }
            short8 s8;
            s8[0]=f2bf(a.x); s8[1]=f2bf(a.y); s8[2]=f2bf(a.z); s8[3]=f2bf(a.w);
            s8[4]=f2bf(b4.x); s8[5]=f2bf(b4.y); s8[6]=f2bf(b4.z); s8[7]=f2bf(b4.w);
            *(short8*)&kt[r][cc] = s8;
        }
        __syncthreads();
        f32x4 sacc = {0.f, 0.f, 0.f, 0.f};
        short8 kb0 = *(const short8*)&kt[w * 16 + c][g * 8];
        short8 kb1 = *(const short8*)&kt[w * 16 + c][32 + g * 8];
        sacc = __builtin_amdgcn_mfma_f32_16x16x32_bf16(qa0, kb0, sacc, 0, 0, 0);
        sacc = __builtin_amdgcn_mfma_f32_16x16x32_bf16(qa1, kb1, sacc, 0, 0, 0);
        int kk = kt0 + w * 16 + c;
        if (kk < 928) {
            #pragma unroll
            for (int j = 0; j < 4; ++j) {
                int qq = q0 + g * 4 + j;
                float val = -1e30f;
                if (kk < S_LEN) {
                    float bias = (qq < S_LEN) ? bgh[(size_t)qq * S_LEN + kk] : 0.f;
                    val = sacc[j] + bias;
                }
                sc[g * 4 + j][kk] = f2bf(val);
            }
        }
    }
    __syncthreads();

    // ---- softmax (wave w owns rows 4w..4w+3); row = 116 x 16B chunks ----
    #pragma unroll
    for (int rr = 0; rr < 4; ++rr) {
        int r = w * 4 + rr;
        short8* rowp = (short8*)&sc[r][0];
        bool has1 = lane < 52;
        short8 c0 = rowp[lane];
        short8 c1 = c0;
        if (has1) c1 = rowp[64 + lane];
        float v0[8], v1[8];
        #pragma unroll
        for (int i = 0; i < 8; ++i) {
            v0[i] = bf2f(c0[i]);
            v1[i] = has1 ? bf2f(c1[i]) : -1e30f;
        }
        float m = -1e30f;
        #pragma unroll
        for (int i = 0; i < 8; ++i) m = fmaxf(m, fmaxf(v0[i], v1[i]));
        #pragma unroll
        for (int off = 32; off >= 1; off >>= 1) m = fmaxf(m, __shfl_xor(m, off));
        float ssum = 0.f;
        #pragma unroll
        for (int i = 0; i < 8; ++i) {
            v0[i] = __expf(v0[i] - m); ssum += v0[i];
            v1[i] = __expf(v1[i] - m); ssum += v1[i];
        }
        #pragma unroll
        for (int off = 32; off >= 1; off >>= 1) ssum += __shfl_xor(ssum, off);
        float inv = 1.f / ssum;
        short8 p0, p1;
        #pragma unroll
        for (int i = 0; i < 8; ++i) {
            p0[i] = f2bf(v0[i] * inv);
            p1[i] = f2bf(v1[i] * inv);
        }
        rowp[lane] = p0;
        if (has1) rowp[64 + lane] = p1;
    }

    // ---- PV ----
    f32x4 oacc = {0.f, 0.f, 0.f, 0.f};
    for (int kt0 = 0; kt0 < S_LEN; kt0 += 64) {
        __syncthreads();
        {
            int d = t & 63, rp0 = t >> 6;
            #pragma unroll
            for (int i = 0; i < 8; ++i) {
                int rp = rp0 + 4 * i;
                int ks = kt0 + 2 * rp;
                float a  = (ks < S_LEN)     ? vbase[(size_t)ks * 1536 + d]       : 0.f;
                float b2 = (ks + 1 < S_LEN) ? vbase[(size_t)(ks + 1) * 1536 + d] : 0.f;
                unsigned pk = (unsigned)(unsigned short)f2bf(a) |
                              ((unsigned)(unsigned short)f2bf(b2) << 16);
                *(unsigned*)((char*)&kt[0][0] + d * 144 + rp * 4) = pk;  // vt[d][k]
            }
        }
        __syncthreads();
        #pragma unroll
        for (int s = 0; s < 2; ++s) {
            if (kt0 + s * 32 < 928) {
                short8 pa = *(const short8*)((const char*)&sc[0][0] + c * 1856 + (kt0 + s * 32 + g * 8) * 2);
                short8 vb = *(const short8*)&kt[w * 16 + c][s * 32 + g * 8];
                oacc = __builtin_amdgcn_mfma_f32_16x16x32_bf16(pa, vb, oacc, 0, 0, 0);
            }
        }
    }
    int d = w * 16 + c;
    #pragma unroll
    for (int j = 0; j < 4; ++j) {
        int q = q0 + g * 4 + j;
        if (q < S_LEN) op[((size_t)(b * S_LEN + q)) * 512 + h * 64 + d] = oacc[j];
    }
}

// ---------------------------------------------------------------------------
// LN: out[row] = LN(src[row] + res[row]) * g + b
// ---------------------------------------------------------------------------
__global__ __launch_bounds__(256) void ln_kernel(
    const float* __restrict__ src, const float* __restrict__ res,
    const float* __restrict__ g, const float* __restrict__ bb,
    float* __restrict__ out) {
    int row = blockIdx.x * 4 + (threadIdx.x >> 6);
    int lane = threadIdx.x & 63;
    const float* s = src + (size_t)row * D_MODEL;
    const float* r = res + (size_t)row * D_MODEL;
    float v[8];
    float tot = 0.f;
    #pragma unroll
    for (int i = 0; i < 8; ++i) {
        int c = lane * 8 + i;
        v[i] = s[c] + r[c];
        tot += v[i];
    }
    #pragma unroll
    for (int off = 32; off >= 1; off >>= 1) tot += __shfl_xor(tot, off);
    float mean = tot * (1.f / 512.f);
    float var = 0.f;
    #pragma unroll
    for (int i = 0; i < 8; ++i) { v[i] -= mean; var += v[i] * v[i]; }
    #pragma unroll
    for (int off = 32; off >= 1; off >>= 1) var += __shfl_xor(var, off);
    float rstd = rsqrtf(var * (1.f / 512.f) + 1e-5f);
    float* o = out + (size_t)row * D_MODEL;
    #pragma unroll
    for (int i = 0; i < 8; ++i) {
        int c = lane * 8 + i;
        o[c] = v[i] * rstd * g[c] + bb[c];
    }
}

__global__ void mean_part_kernel(const float* __restrict__ attn_out, float* __restrict__ partial) {
    int b = blockIdx.x, chunk = blockIdx.y, t = threadIdx.x;
    int s0 = chunk * 100;
    for (int c = t; c < 512; c += 256) {
        float s = 0.f;
        for (int i = 0; i < 100; ++i)
            s += attn_out[((size_t)(b * S_LEN + s0 + i)) * D_MODEL + c];
        partial[((size_t)(b * 9 + chunk)) * 512 + c] = s;
    }
}

__global__ void mean_final_kernel(const float* __restrict__ partial, float* __restrict__ gfeat) {
    int idx = blockIdx.x * 256 + threadIdx.x;
    if (idx >= 16 * 512) return;
    int b = idx / 512, c = idx % 512;
    float s = 0.f;
    for (int i = 0; i < 9; ++i) s += partial[((size_t)(b * 9 + i)) * 512 + c];
    gfeat[idx] = s * (1.0f / 900.0f);
}

__global__ void heads_kernel(const float* __restrict__ gfeat,
    const float* __restrict__ rot_w, const float* __restrict__ rot_b,
    const float* __restrict__ refl_w, const float* __restrict__ refl_b,
    const float* __restrict__ trans_w, const float* __restrict__ trans_b,
    const float* __restrict__ scale_w, const float* __restrict__ scale_b,
    float* __restrict__ dout, float* __restrict__ tp_ws) {
    int b = blockIdx.x, t = threadIdx.x;
    __shared__ float hv[17], tpl[17];
    if (t < 17) {
        const float* wrow; float bb;
        if (t < 4)       { wrow = rot_w + t * 512;          bb = rot_b[t]; }
        else if (t < 12) { wrow = refl_w + (t - 4) * 512;   bb = refl_b[t - 4]; }
        else if (t < 14) { wrow = trans_w + (t - 12) * 512; bb = trans_b[t - 12]; }
        else             { wrow = scale_w + (t - 14) * 512; bb = scale_b[t - 14]; }
        const float* gf = gfeat + b * 512;
        float s = bb;
        for (int i = 0; i < 512; ++i) s += gf[i] * wrow[i];
        if (t == 12 || t == 13) s = tanhf(s);
        hv[t] = s;
    }
    __syncthreads();
    if (t == 0) {
        for (int gidx = 0; gidx < 3; ++gidx) {
            int o = (gidx == 0) ? 0 : (gidx == 1) ? 4 : 14;
            int n = (gidx == 0) ? 4 : (gidx == 1) ? 8 : 3;
            float m = hv[o];
            for (int i = 1; i < n; ++i) m = fmaxf(m, hv[o + i]);
            float sum = 0.f;
            for (int i = 0; i < n; ++i) { float e = expf(hv[o + i] - m); tpl[o + i] = e; sum += e; }
            float inv = 1.f / sum;
            for (int i = 0; i < n; ++i) tpl[o + i] *= inv;
        }
        tpl[12] = hv[12];
        tpl[13] = hv[13];
    }
    __syncthreads();
    if (t < 4)  dout[OFF_ROT + b * 4 + t] = hv[t];
    if (t < 8)  dout[OFF_REFL + b * 8 + t] = hv[4 + t];
    if (t < 2)  dout[OFF_TRANS + b * 2 + t] = hv[12 + t];
    if (t < 3)  dout[OFF_SCAL + b * 3 + t] = hv[14 + t];
    if (t < 17) { dout[OFF_TP + b * 17 + t] = tpl[t]; tp_ws[b * 17 + t] = tpl[t]; }
}

__global__ void ti_kernel(const float* __restrict__ attn_out, const float* __restrict__ tp,
                          float* __restrict__ ti) {
    long idx = (long)blockIdx.x * 256 + threadIdx.x;
    if (idx >= (long)MTOT * 529) return;
    int r = (int)(idx / 529), c = (int)(idx % 529);
    float v;
    if (c < 512) v = attn_out[(size_t)r * 512 + c];
    else         v = tp[(r / S_LEN) * 17 + (c - 512)];
    ti[idx] = v;
}

// ---------------------------------------------------------------------------
extern "C" void kernel_launch(void* const* d_in, const int* in_sizes, int n_in,
                              void* d_out, int out_size, void* d_ws, size_t ws_size,
                              hipStream_t stream) {
    const float* x       = (const float*)d_in[0];
    const float* wq      = (const float*)d_in[1];  const float* bq      = (const float*)d_in[2];
    const float* wk      = (const float*)d_in[3];  const float* bk      = (const float*)d_in[4];
    const float* wv      = (const float*)d_in[5];  const float* bv      = (const float*)d_in[6];
    const float* wo      = (const float*)d_in[7];  const float* bo      = (const float*)d_in[8];
    const float* ln_a_g  = (const float*)d_in[9];  const float* ln_a_b  = (const float*)d_in[10];
    const float* dist_e  = (const float*)d_in[11]; const float* dir_e   = (const float*)d_in[12];
    const float* rot_w   = (const float*)d_in[13]; const float* rot_b   = (const float*)d_in[14];
    const float* refl_w  = (const float*)d_in[15]; const float* refl_b  = (const float*)d_in[16];
    const float* trans_w = (const float*)d_in[17]; const float* trans_b = (const float*)d_in[18];
    const float* scale_w = (const float*)d_in[19]; const float* scale_b = (const float*)d_in[20];
    const float* tn1_w   = (const float*)d_in[21]; const float* tn1_b   = (const float*)d_in[22];
    const float* tn2_w   = (const float*)d_in[23]; const float* tn2_b   = (const float*)d_in[24];
    const float* tn3_w   = (const float*)d_in[25]; const float* tn3_b   = (const float*)d_in[26];
    const float* ff1_w   = (const float*)d_in[27]; const float* ff1_b   = (const float*)d_in[28];
    const float* ff2_w   = (const float*)d_in[29]; const float* ff2_b   = (const float*)d_in[30];
    const float* ln2_g   = (const float*)d_in[31]; const float* ln2_b   = (const float*)d_in[32];
    float* out = (float*)d_out;
    float* ws  = (float*)d_ws;

    // ws layout (floats), lifetime-overlapped
    float* qkv    = ws + 0;         // [M,1536]                     22118400
    float* bufA   = ws + 0;         // T1 (wo out), after attn       7372800
    float* bufB   = ws + 7372800;   // attn_out                      7372800
    float* bufC   = ws + 14745600;  // h2                            7372800
    float* bufE   = ws + 22118400;  // geo bias                      6480000
    float* bufF   = ws + 28598400;  // ti                            7617600
    float* bufG   = ws + 36216000;  // wcat/bcat, later h1/ffo      14745600
    float* bufD   = ws + 50961600;  // attnv, later geo              7372800
    float* gfeat  = ws + 58334400;
    float* partial= ws + 58342592;
    float* tpbuf  = ws + 58416320;
    float* ffh    = ws + 0;         // [M,2048] overlaps dead regions
    float* wcat   = bufG;           // 786432 (dead until tn1 output)
    float* bcat   = bufG + 786432;  // 1536

    dim3 blk(256);
    concat_qkv_kernel<<<3072, blk, 0, stream>>>(wq, wk, wv, bq, bk, bv, wcat, bcat);
    geo_bias_kernel<<<dim3((S_LEN * S_LEN + 255) / 256), blk, 0, stream>>>(dist_e, dir_e, bufE);
    gemm_kernel<<<dim3(12, 113), blk, 0, stream>>>(x, wcat, bcat, nullptr, qkv, MTOT, 1536, 512, 0);
    attn_mfma_kernel<<<dim3(57, 128), blk, 0, stream>>>(qkv, bufE, bufD);
    gemm_kernel<<<dim3(4, 113), blk, 0, stream>>>(bufD, wo, bo, nullptr, bufA, MTOT, 512, 512, 0);
    ln_kernel<<<3600, blk, 0, stream>>>(bufA, x, ln_a_g, ln_a_b, bufB);          // attn_out
    mean_part_kernel<<<dim3(16, 9), blk, 0, stream>>>(bufB, partial);
    mean_final_kernel<<<32, blk, 0, stream>>>(partial, gfeat);
    heads_kernel<<<16, 64, 0, stream>>>(gfeat, rot_w, rot_b, refl_w, refl_b,
                                        trans_w, trans_b, scale_w, scale_b, out, tpbuf);
    ti_kernel<<<(int)(((long)MTOT * 529 + 255) / 256), blk, 0, stream>>>(bufB, tpbuf, bufF);
    gemm_kernel<<<dim3(8, 113), blk, 0, stream>>>(bufF, tn1_w, tn1_b, nullptr, bufG, MTOT, 1024, 529, 1);
    gemm_kernel<<<dim3(4, 113), blk, 0, stream>>>(bufG, tn2_w, tn2_b, nullptr, bufC, MTOT, 512, 1024, 1);
    gemm_kernel<<<dim3(4, 113), blk, 0, stream>>>(bufC, tn3_w, tn3_b, bufB, bufD, MTOT, 512, 512, 2); // geo
    gemm_kernel<<<dim3(16, 113), blk, 0, stream>>>(bufD, ff1_w, ff1_b, nullptr, ffh, MTOT, 2048, 512, 1);
    gemm_kernel<<<dim3(4, 113), blk, 0, stream>>>(ffh, ff2_w, ff2_b, nullptr, bufG, MTOT, 512, 2048, 0);
    ln_kernel<<<3600, blk, 0, stream>>>(bufG, bufD, ln2_g, ln2_b, out);
}

// Round 3
// 1527.342 us; speedup vs baseline: 1.6609x; 1.1309x over previous
//
#include <hip/hip_runtime.h>
#include <cmath>

#define D_MODEL 512
#define S_LEN   900
#define BATCH   16
#define NHEADS  8
#define MTOT    (BATCH * S_LEN)   // 14400

// output layout (floats)
#define OFF_ROT   7372800
#define OFF_REFL  7372864
#define OFF_TRANS 7372992
#define OFF_SCAL  7373024
#define OFF_TP    7373072

typedef float  f32x4   __attribute__((ext_vector_type(4)));
typedef short  short8  __attribute__((ext_vector_type(8)));

__device__ __forceinline__ short f2bf(float f) {
    unsigned u = __builtin_bit_cast(unsigned, f);
    unsigned r = (u + 0x7fffu + ((u >> 16) & 1u)) >> 16;
    return (short)r;
}
__device__ __forceinline__ float bf2f(short s) {
    unsigned u = ((unsigned)(unsigned short)s) << 16;
    return __builtin_bit_cast(float, u);
}

__device__ __forceinline__ float gelu_f(float x) {
    return 0.5f * x * (1.0f + erff(x * 0.70710678118654752440f));
}

// ---------------------------------------------------------------------------
// Generic GEMM: C[M,N] = epilogue(A[M,K] @ W[N,K]^T + bias)
// bf16 MFMA 16x16x32, 128x128 tile, BK=32, 4 waves (2x2), reg-staged LDS.
// mode 0: plain (+bias); 1: gelu; 2: C = res + 0.3*(acc+bias)
// ---------------------------------------------------------------------------
__global__ __launch_bounds__(256) void gemm_kernel(
    const float* __restrict__ A, const float* __restrict__ W,
    const float* __restrict__ bias, const float* __restrict__ res,
    float* __restrict__ C, int Mr, int N, int K, int mode) {
    __shared__ short As[128 * 40];
    __shared__ short Bs[128 * 40];
    const int t    = threadIdx.x;
    const int bn   = blockIdx.x, bm = blockIdx.y;
    const int row  = t >> 1;
    const int koff = (t & 1) * 16;
    const int wid  = t >> 6, lane = t & 63;
    const int wm   = wid >> 1, wn = wid & 1;
    const int lr   = lane & 15;
    const int ko8  = (lane >> 4) * 8;
    const bool k4  = (K & 3) == 0;
    const int arow = bm * 128 + row;
    const int wrow = bn * 128 + row;
    const int nk   = (K + 31) / 32;

    f32x4 acc[4][4] = {};

    for (int kt = 0; kt < nk; ++kt) {
        const int k0 = kt * 32;
        float va[16];
        if (k4 && arow < Mr && (k0 + koff + 16) <= K) {
            const float4* p = (const float4*)(A + (size_t)arow * K + k0 + koff);
            float4 x0 = p[0], x1 = p[1], x2 = p[2], x3 = p[3];
            va[0]=x0.x; va[1]=x0.y; va[2]=x0.z; va[3]=x0.w;
            va[4]=x1.x; va[5]=x1.y; va[6]=x1.z; va[7]=x1.w;
            va[8]=x2.x; va[9]=x2.y; va[10]=x2.z; va[11]=x2.w;
            va[12]=x3.x; va[13]=x3.y; va[14]=x3.z; va[15]=x3.w;
        } else {
            #pragma unroll
            for (int j = 0; j < 16; ++j) {
                int kk = k0 + koff + j;
                va[j] = (arow < Mr && kk < K) ? A[(size_t)arow * K + kk] : 0.f;
            }
        }
        float vb[16];
        if (k4 && (k0 + koff + 16) <= K) {
            const float4* p = (const float4*)(W + (size_t)wrow * K + k0 + koff);
            float4 x0 = p[0], x1 = p[1], x2 = p[2], x3 = p[3];
            vb[0]=x0.x; vb[1]=x0.y; vb[2]=x0.z; vb[3]=x0.w;
            vb[4]=x1.x; vb[5]=x1.y; vb[6]=x1.z; vb[7]=x1.w;
            vb[8]=x2.x; vb[9]=x2.y; vb[10]=x2.z; vb[11]=x2.w;
            vb[12]=x3.x; vb[13]=x3.y; vb[14]=x3.z; vb[15]=x3.w;
        } else {
            #pragma unroll
            for (int j = 0; j < 16; ++j) {
                int kk = k0 + koff + j;
                vb[j] = (kk < K) ? W[(size_t)wrow * K + kk] : 0.f;
            }
        }
        short8 sa0, sa1, sb0, sb1;
        #pragma unroll
        for (int j = 0; j < 8; ++j) {
            sa0[j] = f2bf(va[j]);  sa1[j] = f2bf(va[8 + j]);
            sb0[j] = f2bf(vb[j]);  sb1[j] = f2bf(vb[8 + j]);
        }
        *(short8*)&As[row * 40 + koff]     = sa0;
        *(short8*)&As[row * 40 + koff + 8] = sa1;
        *(short8*)&Bs[row * 40 + koff]     = sb0;
        *(short8*)&Bs[row * 40 + koff + 8] = sb1;
        __syncthreads();

        short8 af[4], bf[4];
        #pragma unroll
        for (int m = 0; m < 4; ++m)
            af[m] = *(const short8*)&As[(wm * 64 + m * 16 + lr) * 40 + ko8];
        #pragma unroll
        for (int n = 0; n < 4; ++n)
            bf[n] = *(const short8*)&Bs[(wn * 64 + n * 16 + lr) * 40 + ko8];
        #pragma unroll
        for (int m = 0; m < 4; ++m)
            #pragma unroll
            for (int n = 0; n < 4; ++n)
                acc[m][n] = __builtin_amdgcn_mfma_f32_16x16x32_bf16(af[m], bf[n], acc[m][n], 0, 0, 0);
        __syncthreads();
    }

    #pragma unroll
    for (int m = 0; m < 4; ++m) {
        int grow_base = bm * 128 + wm * 64 + m * 16 + (lane >> 4) * 4;
        #pragma unroll
        for (int j = 0; j < 4; ++j) {
            int grow = grow_base + j;
            if (grow >= Mr) continue;
            #pragma unroll
            for (int n = 0; n < 4; ++n) {
                int gcol = bn * 128 + wn * 64 + n * 16 + lr;
                float v = acc[m][n][j] + bias[gcol];
                if (mode == 1) v = gelu_f(v);
                else if (mode == 2) v = res[(size_t)grow * N + gcol] + 0.3f * v;
                C[(size_t)grow * N + gcol] = v;
            }
        }
    }
}

// ---------------------------------------------------------------------------
// concat wq/wk/wv -> wcat[1536][512], biases -> bcat[1536]
// ---------------------------------------------------------------------------
__global__ void concat_qkv_kernel(
    const float* __restrict__ wq, const float* __restrict__ wk, const float* __restrict__ wv,
    const float* __restrict__ bq, const float* __restrict__ bk, const float* __restrict__ bv,
    float* __restrict__ wcat, float* __restrict__ bcat) {
    int idx = blockIdx.x * 256 + threadIdx.x;
    if (idx < 1536)
        bcat[idx] = (idx < 512) ? bq[idx] : (idx < 1024) ? bk[idx - 512] : bv[idx - 1024];
    if (idx >= 1536 * 512) return;
    int n = idx >> 9, cc = idx & 511;
    const float* src = (n < 512) ? wq : (n < 1024) ? wk : wv;
    wcat[idx] = src[(n & 511) * 512 + cc];
}

// ---------------------------------------------------------------------------
// geo bias -> bf16 table bgb[8][900][928], cols >= 900 filled with -1e30
// ---------------------------------------------------------------------------
__global__ void geo_bias_kernel(const float* __restrict__ dist_emb,
                                const float* __restrict__ dir_emb,
                                short* __restrict__ bgb) {
    int idx = blockIdx.x * 256 + threadIdx.x;
    if (idx >= S_LEN * 928) return;
    int q = idx / 928, k = idx % 928;
    if (k >= S_LEN) {
        short pad = f2bf(-1e30f);
        #pragma unroll
        for (int hd = 0; hd < 8; ++hd)
            bgb[((size_t)hd * S_LEN + q) * 928 + k] = pad;
        return;
    }
    int h1 = q / 30, w1 = q % 30;
    int h2 = k / 30, w2 = k % 30;
    int dh = h2 - h1, dw = w2 - w1;
    int dist = min((int)floorf(sqrtf((float)(dh * dh + dw * dw))), 59);
    int dir = 0;
    if (dh != 0 || dw != 0) {
        const float PI_F = 3.14159265358979323846f;
        float ang = atan2f((float)dh, (float)dw);
        dir = ((int)floorf((ang + PI_F) / (PI_F * 0.25f))) & 7;
    }
    #pragma unroll
    for (int hd = 0; hd < 8; ++hd)
        bgb[((size_t)hd * S_LEN + q) * 928 + k] = f2bf(dist_emb[dist * 8 + hd] + dir_emb[dir * 8 + hd]);
}

// ---------------------------------------------------------------------------
// MFMA attention v3. qkv: [B,S,1536] (q +0, k +512, v +1024). bgb bf16 table.
// Block = (b,h) x 32-q-row tile, 4 waves. Wave w owns k/d subtile w*16..+15.
// LDS: sc[32][936] bf16 scores/P; kt[64][64] XOR-swizzled K tile / V^T tile.
// ---------------------------------------------------------------------------
__global__ __launch_bounds__(256) void attn_mfma_kernel(
    const float* __restrict__ qkv, const short* __restrict__ bgb,
    float* __restrict__ op) {
    __shared__ short sc[32 * 936];
    __shared__ short kt[64 * 64];
    __shared__ short qt[32 * 64];
    const int t = threadIdx.x;
    const int w = t >> 6, lane = t & 63;
    const int c = lane & 15, g = lane >> 4;
    const int bh = blockIdx.y, b = bh >> 3, h = bh & 7;
    const int q0 = blockIdx.x * 32;
    const float* qbase = qkv + (size_t)b * S_LEN * 1536 + h * 64;
    const float* kbase = qbase + 512;
    const float* vbase = qbase + 1024;

    // ---- stage Q (scale 1/8) ----
    {
        int r = t >> 3, cc = (t & 7) * 8;
        int qs = q0 + r;
        float4 a = {0.f,0.f,0.f,0.f}, d4 = {0.f,0.f,0.f,0.f};
        if (qs < S_LEN) {
            a  = *(const float4*)(qbase + (size_t)qs * 1536 + cc);
            d4 = *(const float4*)(qbase + (size_t)qs * 1536 + cc + 4);
        }
        short8 s8;
        s8[0]=f2bf(a.x*0.125f); s8[1]=f2bf(a.y*0.125f); s8[2]=f2bf(a.z*0.125f); s8[3]=f2bf(a.w*0.125f);
        s8[4]=f2bf(d4.x*0.125f); s8[5]=f2bf(d4.y*0.125f); s8[6]=f2bf(d4.z*0.125f); s8[7]=f2bf(d4.w*0.125f);
        *(short8*)&qt[r * 64 + cc] = s8;
    }
    __syncthreads();
    short8 qa[2][2];
    #pragma unroll
    for (int qtile = 0; qtile < 2; ++qtile)
        #pragma unroll
        for (int s = 0; s < 2; ++s)
            qa[qtile][s] = *(const short8*)&qt[(qtile * 16 + c) * 64 + 32 * s + g * 8];

    // ---- QK^T ----
    for (int kt0 = 0; kt0 < S_LEN; kt0 += 64) {
        __syncthreads();
        #pragma unroll
        for (int p = 0; p < 2; ++p) {
            int r = (t >> 3) + 32 * p, cc = (t & 7) * 8;
            int ks = kt0 + r;
            float4 a = {0.f,0.f,0.f,0.f}, d4 = {0.f,0.f,0.f,0.f};
            if (ks < S_LEN) {
                a  = *(const float4*)(kbase + (size_t)ks * 1536 + cc);
                d4 = *(const float4*)(kbase + (size_t)ks * 1536 + cc + 4);
            }
            short8 s8;
            s8[0]=f2bf(a.x); s8[1]=f2bf(a.y); s8[2]=f2bf(a.z); s8[3]=f2bf(a.w);
            s8[4]=f2bf(d4.x); s8[5]=f2bf(d4.y); s8[6]=f2bf(d4.z); s8[7]=f2bf(d4.w);
            *(short8*)&kt[r * 64 + (cc ^ ((r & 7) * 8))] = s8;
        }
        __syncthreads();
        f32x4 sacc[2] = {{0.f,0.f,0.f,0.f},{0.f,0.f,0.f,0.f}};
        int n = w * 16 + c;
        #pragma unroll
        for (int s = 0; s < 2; ++s) {
            short8 kb = *(const short8*)&kt[n * 64 + ((32 * s + g * 8) ^ ((n & 7) * 8))];
            sacc[0] = __builtin_amdgcn_mfma_f32_16x16x32_bf16(qa[0][s], kb, sacc[0], 0, 0, 0);
            sacc[1] = __builtin_amdgcn_mfma_f32_16x16x32_bf16(qa[1][s], kb, sacc[1], 0, 0, 0);
        }
        int kk = kt0 + n;
        if (kk < 928) {
            #pragma unroll
            for (int qtile = 0; qtile < 2; ++qtile)
                #pragma unroll
                for (int j = 0; j < 4; ++j)
                    sc[(qtile * 16 + g * 4 + j) * 936 + kk] = f2bf(sacc[qtile][j]);
        }
    }
    __syncthreads();

    // ---- softmax + bias (wave w owns rows w*8..w*8+7); 116 short8 chunks ----
    #pragma unroll
    for (int rr = 0; rr < 8; ++rr) {
        int r = w * 8 + rr;
        int q = q0 + r;
        short8* rowp = (short8*)&sc[r * 936];
        bool has1 = lane < 52;
        if (q < S_LEN) {
            const short8* brow = (const short8*)(bgb + ((size_t)h * S_LEN + q) * 928);
            short8 c0 = rowp[lane], b0 = brow[lane];
            short8 c1 = c0, b1 = b0;
            if (has1) { c1 = rowp[64 + lane]; b1 = brow[64 + lane]; }
            float v0[8], v1[8];
            #pragma unroll
            for (int i = 0; i < 8; ++i) {
                v0[i] = bf2f(c0[i]) + bf2f(b0[i]);
                v1[i] = has1 ? (bf2f(c1[i]) + bf2f(b1[i])) : -1e30f;
            }
            float m = -1e30f;
            #pragma unroll
            for (int i = 0; i < 8; ++i) m = fmaxf(m, fmaxf(v0[i], v1[i]));
            #pragma unroll
            for (int off = 32; off >= 1; off >>= 1) m = fmaxf(m, __shfl_xor(m, off));
            float ssum = 0.f;
            #pragma unroll
            for (int i = 0; i < 8; ++i) {
                v0[i] = __expf(v0[i] - m); ssum += v0[i];
                v1[i] = __expf(v1[i] - m); ssum += v1[i];
            }
            #pragma unroll
            for (int off = 32; off >= 1; off >>= 1) ssum += __shfl_xor(ssum, off);
            float inv = 1.f / ssum;
            short8 p0, p1;
            #pragma unroll
            for (int i = 0; i < 8; ++i) {
                p0[i] = f2bf(v0[i] * inv);
                p1[i] = f2bf(v1[i] * inv);
            }
            rowp[lane] = p0;
            if (has1) rowp[64 + lane] = p1;
        } else {
            short8 z = {0,0,0,0,0,0,0,0};
            rowp[lane] = z;
            if (has1) rowp[64 + lane] = z;
        }
    }

    // ---- PV ----
    f32x4 oacc[2] = {{0.f,0.f,0.f,0.f},{0.f,0.f,0.f,0.f}};
    for (int kt0 = 0; kt0 < S_LEN; kt0 += 64) {
        __syncthreads();
        {
            int d = t & 63, rp0 = t >> 6;
            #pragma unroll
            for (int i = 0; i < 8; ++i) {
                int rp = rp0 + 4 * i;
                int ks = kt0 + 2 * rp;
                float a  = (ks < S_LEN)     ? vbase[(size_t)ks * 1536 + d]       : 0.f;
                float b2 = (ks + 1 < S_LEN) ? vbase[(size_t)(ks + 1) * 1536 + d] : 0.f;
                unsigned pk = (unsigned)(unsigned short)f2bf(a) |
                              ((unsigned)(unsigned short)f2bf(b2) << 16);
                *(unsigned*)&kt[d * 64 + ((2 * rp) ^ ((d & 7) * 8))] = pk;   // vt[d][k]
            }
        }
        __syncthreads();
        int n = w * 16 + c;
        #pragma unroll
        for (int s = 0; s < 2; ++s) {
            if (kt0 + 32 * s < 928) {
                short8 vb = *(const short8*)&kt[n * 64 + ((32 * s + g * 8) ^ ((n & 7) * 8))];
                #pragma unroll
                for (int qtile = 0; qtile < 2; ++qtile) {
                    short8 pa = *(const short8*)&sc[(qtile * 16 + c) * 936 + kt0 + 32 * s + g * 8];
                    oacc[qtile] = __builtin_amdgcn_mfma_f32_16x16x32_bf16(pa, vb, oacc[qtile], 0, 0, 0);
                }
            }
        }
    }
    int d = w * 16 + c;
    #pragma unroll
    for (int qtile = 0; qtile < 2; ++qtile)
        #pragma unroll
        for (int j = 0; j < 4; ++j) {
            int q = q0 + qtile * 16 + g * 4 + j;
            if (q < S_LEN) op[((size_t)(b * S_LEN + q)) * 512 + h * 64 + d] = oacc[qtile][j];
        }
}

// ---------------------------------------------------------------------------
// LN: out[row] = LN(src[row] + res[row]) * g + b
// ---------------------------------------------------------------------------
__global__ __launch_bounds__(256) void ln_kernel(
    const float* __restrict__ src, const float* __restrict__ res,
    const float* __restrict__ g, const float* __restrict__ bb,
    float* __restrict__ out) {
    int row = blockIdx.x * 4 + (threadIdx.x >> 6);
    int lane = threadIdx.x & 63;
    const float* s = src + (size_t)row * D_MODEL;
    const float* r = res + (size_t)row * D_MODEL;
    float v[8];
    float tot = 0.f;
    #pragma unroll
    for (int i = 0; i < 8; ++i) {
        int c = lane * 8 + i;
        v[i] = s[c] + r[c];
        tot += v[i];
    }
    #pragma unroll
    for (int off = 32; off >= 1; off >>= 1) tot += __shfl_xor(tot, off);
    float mean = tot * (1.f / 512.f);
    float var = 0.f;
    #pragma unroll
    for (int i = 0; i < 8; ++i) { v[i] -= mean; var += v[i] * v[i]; }
    #pragma unroll
    for (int off = 32; off >= 1; off >>= 1) var += __shfl_xor(var, off);
    float rstd = rsqrtf(var * (1.f / 512.f) + 1e-5f);
    float* o = out + (size_t)row * D_MODEL;
    #pragma unroll
    for (int i = 0; i < 8; ++i) {
        int c = lane * 8 + i;
        o[c] = v[i] * rstd * g[c] + bb[c];
    }
}

__global__ void mean_part_kernel(const float* __restrict__ attn_out, float* __restrict__ partial) {
    int b = blockIdx.x, chunk = blockIdx.y, t = threadIdx.x;
    int s0 = chunk * 100;
    for (int c = t; c < 512; c += 256) {
        float s = 0.f;
        for (int i = 0; i < 100; ++i)
            s += attn_out[((size_t)(b * S_LEN + s0 + i)) * D_MODEL + c];
        partial[((size_t)(b * 9 + chunk)) * 512 + c] = s;
    }
}

__global__ void mean_final_kernel(const float* __restrict__ partial, float* __restrict__ gfeat) {
    int idx = blockIdx.x * 256 + threadIdx.x;
    if (idx >= 16 * 512) return;
    int b = idx / 512, c = idx % 512;
    float s = 0.f;
    for (int i = 0; i < 9; ++i) s += partial[((size_t)(b * 9 + i)) * 512 + c];
    gfeat[idx] = s * (1.0f / 900.0f);
}

__global__ void heads_kernel(const float* __restrict__ gfeat,
    const float* __restrict__ rot_w, const float* __restrict__ rot_b,
    const float* __restrict__ refl_w, const float* __restrict__ refl_b,
    const float* __restrict__ trans_w, const float* __restrict__ trans_b,
    const float* __restrict__ scale_w, const float* __restrict__ scale_b,
    float* __restrict__ dout, float* __restrict__ tp_ws) {
    int b = blockIdx.x, t = threadIdx.x;
    __shared__ float hv[17], tpl[17];
    if (t < 17) {
        const float* wrow; float bb;
        if (t < 4)       { wrow = rot_w + t * 512;          bb = rot_b[t]; }
        else if (t < 12) { wrow = refl_w + (t - 4) * 512;   bb = refl_b[t - 4]; }
        else if (t < 14) { wrow = trans_w + (t - 12) * 512; bb = trans_b[t - 12]; }
        else             { wrow = scale_w + (t - 14) * 512; bb = scale_b[t - 14]; }
        const float* gf = gfeat + b * 512;
        float s = bb;
        for (int i = 0; i < 512; ++i) s += gf[i] * wrow[i];
        if (t == 12 || t == 13) s = tanhf(s);
        hv[t] = s;
    }
    __syncthreads();
    if (t == 0) {
        for (int gidx = 0; gidx < 3; ++gidx) {
            int o = (gidx == 0) ? 0 : (gidx == 1) ? 4 : 14;
            int n = (gidx == 0) ? 4 : (gidx == 1) ? 8 : 3;
            float m = hv[o];
            for (int i = 1; i < n; ++i) m = fmaxf(m, hv[o + i]);
            float sum = 0.f;
            for (int i = 0; i < n; ++i) { float e = expf(hv[o + i] - m); tpl[o + i] = e; sum += e; }
            float inv = 1.f / sum;
            for (int i = 0; i < n; ++i) tpl[o + i] *= inv;
        }
        tpl[12] = hv[12];
        tpl[13] = hv[13];
    }
    __syncthreads();
    if (t < 4)  dout[OFF_ROT + b * 4 + t] = hv[t];
    if (t < 8)  dout[OFF_REFL + b * 8 + t] = hv[4 + t];
    if (t < 2)  dout[OFF_TRANS + b * 2 + t] = hv[12 + t];
    if (t < 3)  dout[OFF_SCAL + b * 3 + t] = hv[14 + t];
    if (t < 17) { dout[OFF_TP + b * 17 + t] = tpl[t]; tp_ws[b * 17 + t] = tpl[t]; }
}

__global__ void ti_kernel(const float* __restrict__ attn_out, const float* __restrict__ tp,
                          float* __restrict__ ti) {
    long idx = (long)blockIdx.x * 256 + threadIdx.x;
    if (idx >= (long)MTOT * 529) return;
    int r = (int)(idx / 529), c = (int)(idx % 529);
    float v;
    if (c < 512) v = attn_out[(size_t)r * 512 + c];
    else         v = tp[(r / S_LEN) * 17 + (c - 512)];
    ti[idx] = v;
}

// ---------------------------------------------------------------------------
extern "C" void kernel_launch(void* const* d_in, const int* in_sizes, int n_in,
                              void* d_out, int out_size, void* d_ws, size_t ws_size,
                              hipStream_t stream) {
    const float* x       = (const float*)d_in[0];
    const float* wq      = (const float*)d_in[1];  const float* bq      = (const float*)d_in[2];
    const float* wk      = (const float*)d_in[3];  const float* bk      = (const float*)d_in[4];
    const float* wv      = (const float*)d_in[5];  const float* bv      = (const float*)d_in[6];
    const float* wo      = (const float*)d_in[7];  const float* bo      = (const float*)d_in[8];
    const float* ln_a_g  = (const float*)d_in[9];  const float* ln_a_b  = (const float*)d_in[10];
    const float* dist_e  = (const float*)d_in[11]; const float* dir_e   = (const float*)d_in[12];
    const float* rot_w   = (const float*)d_in[13]; const float* rot_b   = (const float*)d_in[14];
    const float* refl_w  = (const float*)d_in[15]; const float* refl_b  = (const float*)d_in[16];
    const float* trans_w = (const float*)d_in[17]; const float* trans_b = (const float*)d_in[18];
    const float* scale_w = (const float*)d_in[19]; const float* scale_b = (const float*)d_in[20];
    const float* tn1_w   = (const float*)d_in[21]; const float* tn1_b   = (const float*)d_in[22];
    const float* tn2_w   = (const float*)d_in[23]; const float* tn2_b   = (const float*)d_in[24];
    const float* tn3_w   = (const float*)d_in[25]; const float* tn3_b   = (const float*)d_in[26];
    const float* ff1_w   = (const float*)d_in[27]; const float* ff1_b   = (const float*)d_in[28];
    const float* ff2_w   = (const float*)d_in[29]; const float* ff2_b   = (const float*)d_in[30];
    const float* ln2_g   = (const float*)d_in[31]; const float* ln2_b   = (const float*)d_in[32];
    float* out = (float*)d_out;
    float* ws  = (float*)d_ws;

    // ws layout (floats), lifetime-overlapped
    float* qkv    = ws + 0;         // [M,1536]                     22118400
    float* bufA   = ws + 0;         // T1 (wo out), after attn       7372800
    float* bufB   = ws + 7372800;   // attn_out                      7372800
    float* bufC   = ws + 14745600;  // h2                            7372800
    float* bufE   = ws + 22118400;  // geo bias bf16 table           6480000
    float* bufF   = ws + 28598400;  // ti                            7617600
    float* bufG   = ws + 36216000;  // wcat/bcat, later h1/ffo      14745600
    float* bufD   = ws + 50961600;  // attnv, later geo              7372800
    float* gfeat  = ws + 58334400;
    float* partial= ws + 58342592;
    float* tpbuf  = ws + 58416320;
    float* ffh    = ws + 0;         // [M,2048] overlaps dead regions
    float* wcat   = bufG;           // 786432 (dead until tn1 output)
    float* bcat   = bufG + 786432;  // 1536
    short* bgb    = (short*)bufE;   // [8][900][928] bf16 = 13.4 MB

    dim3 blk(256);
    concat_qkv_kernel<<<3072, blk, 0, stream>>>(wq, wk, wv, bq, bk, bv, wcat, bcat);
    geo_bias_kernel<<<dim3((S_LEN * 928 + 255) / 256), blk, 0, stream>>>(dist_e, dir_e, bgb);
    gemm_kernel<<<dim3(12, 113), blk, 0, stream>>>(x, wcat, bcat, nullptr, qkv, MTOT, 1536, 512, 0);
    attn_mfma_kernel<<<dim3(29, 128), blk, 0, stream>>>(qkv, bgb, bufD);
    gemm_kernel<<<dim3(4, 113), blk, 0, stream>>>(bufD, wo, bo, nullptr, bufA, MTOT, 512, 512, 0);
    ln_kernel<<<3600, blk, 0, stream>>>(bufA, x, ln_a_g, ln_a_b, bufB);          // attn_out
    mean_part_kernel<<<dim3(16, 9), blk, 0, stream>>>(bufB, partial);
    mean_final_kernel<<<32, blk, 0, stream>>>(partial, gfeat);
    heads_kernel<<<16, 64, 0, stream>>>(gfeat, rot_w, rot_b, refl_w, refl_b,
                                        trans_w, trans_b, scale_w, scale_b, out, tpbuf);
    ti_kernel<<<(int)(((long)MTOT * 529 + 255) / 256), blk, 0, stream>>>(bufB, tpbuf, bufF);
    gemm_kernel<<<dim3(8, 113), blk, 0, stream>>>(bufF, tn1_w, tn1_b, nullptr, bufG, MTOT, 1024, 529, 1);
    gemm_kernel<<<dim3(4, 113), blk, 0, stream>>>(bufG, tn2_w, tn2_b, nullptr, bufC, MTOT, 512, 1024, 1);
    gemm_kernel<<<dim3(4, 113), blk, 0, stream>>>(bufC, tn3_w, tn3_b, bufB, bufD, MTOT, 512, 512, 2); // geo
    gemm_kernel<<<dim3(16, 113), blk, 0, stream>>>(bufD, ff1_w, ff1_b, nullptr, ffh, MTOT, 2048, 512, 1);
    gemm_kernel<<<dim3(4, 113), blk, 0, stream>>>(ffh, ff2_w, ff2_b, nullptr, bufG, MTOT, 512, 2048, 0);
    ln_kernel<<<3600, blk, 0, stream>>>(bufG, bufD, ln2_g, ln2_b, out);
}

// Round 4
// 822.586 us; speedup vs baseline: 3.0838x; 1.8568x over previous
//
#include <hip/hip_runtime.h>
#include <cmath>

#define D_MODEL 512
#define S_LEN   900
#define BATCH   16
#define NHEADS  8
#define MTOT    (BATCH * S_LEN)   // 14400

// output layout (floats)
#define OFF_ROT   7372800
#define OFF_REFL  7372864
#define OFF_TRANS 7372992
#define OFF_SCAL  7373024
#define OFF_TP    7373072

typedef float  f32x4   __attribute__((ext_vector_type(4)));
typedef short  short8  __attribute__((ext_vector_type(8)));

#define MFMA16 __builtin_amdgcn_mfma_f32_16x16x32_bf16
#define GLD16(gp, lp) __builtin_amdgcn_global_load_lds((const unsigned int*)(gp), (unsigned int*)(lp), 16, 0, 0)

__device__ __forceinline__ short f2bf(float f) {
    unsigned u = __builtin_bit_cast(unsigned, f);
    unsigned r = (u + 0x7fffu + ((u >> 16) & 1u)) >> 16;
    return (short)r;
}
__device__ __forceinline__ float bf2f(short s) {
    unsigned u = ((unsigned)(unsigned short)s) << 16;
    return __builtin_bit_cast(float, u);
}
__device__ __forceinline__ float gelu_f(float x) {
    return 0.5f * x * (1.0f + erff(x * 0.70710678118654752440f));
}

// ---------------------------------------------------------------------------
// prep: convert weights (+concat qkv, +pad tn1 to K=544) and x to bf16
// wreg layout (shorts): wcat@0[1536x512], wo@786432, tn1p@1048576[1024x544],
// tn2@1605632, tn3@2129920, ff1@2392064, ff2@3440640, total 4489216
// ---------------------------------------------------------------------------
__global__ void prep_kernel(
    const float* __restrict__ wq, const float* __restrict__ wk, const float* __restrict__ wv,
    const float* __restrict__ wo, const float* __restrict__ tn1w, const float* __restrict__ tn2w,
    const float* __restrict__ tn3w, const float* __restrict__ ff1w, const float* __restrict__ ff2w,
    const float* __restrict__ bq, const float* __restrict__ bk, const float* __restrict__ bv,
    const float* __restrict__ x, short* __restrict__ wdst, float* __restrict__ bcat,
    short* __restrict__ xb) {
    long i = (long)blockIdx.x * 256 + threadIdx.x;
    if (i < 786432) {
        int nidx = (int)(i >> 9), cc = (int)(i & 511);
        const float* s = nidx < 512 ? wq : nidx < 1024 ? wk : wv;
        wdst[i] = f2bf(s[(nidx & 511) * 512 + cc]);
    } else if (i < 1048576) {
        wdst[i] = f2bf(wo[i - 786432]);
    } else if (i < 1605632) {
        long j = i - 1048576; int r = (int)(j / 544), cc = (int)(j % 544);
        wdst[i] = cc < 529 ? f2bf(tn1w[r * 529 + cc]) : (short)0;
    } else if (i < 2129920) {
        wdst[i] = f2bf(tn2w[i - 1605632]);
    } else if (i < 2392064) {
        wdst[i] = f2bf(tn3w[i - 2129920]);
    } else if (i < 3440640) {
        wdst[i] = f2bf(ff1w[i - 2392064]);
    } else if (i < 4489216) {
        wdst[i] = f2bf(ff2w[i - 3440640]);
    } else if (i < 4490752) {
        int j = (int)(i - 4489216);
        bcat[j] = j < 512 ? bq[j] : j < 1024 ? bk[j - 512] : bv[j - 1024];
    } else if (i < 11863552) {
        long j = i - 4490752;
        xb[j] = f2bf(x[j]);
    }
}

// ---------------------------------------------------------------------------
// GEMM (m97 structure): C[M,N](bf16) = epi(A[M,K]bf16 @ W[N,K]^T bf16 + bias)
// 128x128 tile, BK=32, 4 waves, global_load_lds width-16, linear LDS.
// mode 0: plain; 1: gelu; 2: C = res(bf16) + 0.3*(acc+bias)
// ---------------------------------------------------------------------------
__global__ __launch_bounds__(256) void gemm_kernel(
    const short* __restrict__ A, const short* __restrict__ W,
    const float* __restrict__ bias, const short* __restrict__ res,
    short* __restrict__ C, int M, int N, int K, int mode) {
    __shared__ short As[4096];
    __shared__ short Bs[4096];
    const int t = threadIdx.x;
    const int bn = blockIdx.x, bm = blockIdx.y;
    const int wid = t >> 6, lane = t & 63;
    const int wm = wid >> 1, wn = wid & 1;
    const int lr = lane & 15, g4 = lane >> 4;
    const int srow = t >> 2;
    const int sg = (t & 3) * 8;
    long a0 = (long)bm * 128 + srow;       if (a0 > M - 1) a0 = M - 1;
    long a1 = (long)bm * 128 + srow + 64;  if (a1 > M - 1) a1 = M - 1;
    const short* ap0 = A + a0 * K + sg;
    const short* ap1 = A + a1 * K + sg;
    const short* bp0 = W + ((long)bn * 128 + srow) * K + sg;
    const short* bp1 = W + ((long)bn * 128 + srow + 64) * K + sg;
    short* la = As + wid * 512;
    short* lb = Bs + wid * 512;

    f32x4 acc[4][4] = {};
    const int nk = K >> 5;
    for (int kt = 0; kt < nk; ++kt) {
        const int k0 = kt << 5;
        GLD16(ap0 + k0, la);
        GLD16(ap1 + k0, la + 2048);
        GLD16(bp0 + k0, lb);
        GLD16(bp1 + k0, lb + 2048);
        __syncthreads();
        short8 af[4], bfr[4];
        #pragma unroll
        for (int m = 0; m < 4; ++m)
            af[m] = *(const short8*)&As[(wm * 64 + m * 16 + lr) * 32 + g4 * 8];
        #pragma unroll
        for (int nn = 0; nn < 4; ++nn)
            bfr[nn] = *(const short8*)&Bs[(wn * 64 + nn * 16 + lr) * 32 + g4 * 8];
        #pragma unroll
        for (int m = 0; m < 4; ++m)
            #pragma unroll
            for (int nn = 0; nn < 4; ++nn)
                acc[m][nn] = MFMA16(af[m], bfr[nn], acc[m][nn], 0, 0, 0);
        __syncthreads();
    }

    #pragma unroll
    for (int m = 0; m < 4; ++m) {
        int gr0 = bm * 128 + wm * 64 + m * 16 + g4 * 4;
        #pragma unroll
        for (int j = 0; j < 4; ++j) {
            int grow = gr0 + j;
            if (grow >= M) continue;
            #pragma unroll
            for (int nn = 0; nn < 4; ++nn) {
                int gcol = bn * 128 + wn * 64 + nn * 16 + lr;
                float v = acc[m][nn][j] + bias[gcol];
                if (mode == 1) v = gelu_f(v);
                else if (mode == 2) v = bf2f(res[(size_t)grow * N + gcol]) + 0.3f * v;
                C[(size_t)grow * N + gcol] = f2bf(v);
            }
        }
    }
}

// ---------------------------------------------------------------------------
// geo bias -> bf16 table bgb[8][900][928], cols >= 900 = -1e30
// ---------------------------------------------------------------------------
__global__ void geo_bias_kernel(const float* __restrict__ dist_emb,
                                const float* __restrict__ dir_emb,
                                short* __restrict__ bgb) {
    int idx = blockIdx.x * 256 + threadIdx.x;
    if (idx >= S_LEN * 928) return;
    int q = idx / 928, k = idx % 928;
    if (k >= S_LEN) {
        short pad = f2bf(-1e30f);
        #pragma unroll
        for (int hd = 0; hd < 8; ++hd)
            bgb[((size_t)hd * S_LEN + q) * 928 + k] = pad;
        return;
    }
    int h1 = q / 30, h2 = k / 30;
    int dh = h2 - h1, dw = (k % 30) - (q % 30);
    int dist = min((int)floorf(sqrtf((float)(dh * dh + dw * dw))), 59);
    int dir = 0;
    if (dh != 0 || dw != 0) {
        const float PI_F = 3.14159265358979323846f;
        float ang = atan2f((float)dh, (float)dw);
        dir = ((int)floorf((ang + PI_F) / (PI_F * 0.25f))) & 7;
    }
    #pragma unroll
    for (int hd = 0; hd < 8; ++hd)
        bgb[((size_t)hd * S_LEN + q) * 928 + k] = f2bf(dist_emb[dist * 8 + hd] + dir_emb[dir * 8 + hd]);
}

// ---------------------------------------------------------------------------
// V^T: qkvb[M,1536] (v at +1024) -> vtb[b][h][64][928] bf16, k>=900 zeros
// ---------------------------------------------------------------------------
__global__ __launch_bounds__(256) void vt_kernel(const short* __restrict__ qkvb,
                                                 short* __restrict__ vtb) {
    __shared__ short tile[64][72];
    const int bh = blockIdx.y, b = bh >> 3, h = bh & 7;
    const int kt0 = blockIdx.x * 64;
    const int t = threadIdx.x;
    const int r = t >> 3, cg = (t & 7) * 8;
    #pragma unroll
    for (int p = 0; p < 2; ++p) {
        int rr = r + 32 * p;
        int k = kt0 + rr;
        short8 v = {0, 0, 0, 0, 0, 0, 0, 0};
        if (k < S_LEN) v = *(const short8*)&qkvb[((size_t)(b * S_LEN) + k) * 1536 + 1024 + h * 64 + cg];
        *(short8*)&tile[rr][cg] = v;
    }
    __syncthreads();
    #pragma unroll
    for (int p = 0; p < 2; ++p) {
        int d = r + 32 * p;
        int kk = kt0 + cg;
        if (kk < 928) {
            short8 v;
            #pragma unroll
            for (int i = 0; i < 8; ++i) v[i] = tile[cg + i][d];
            *(short8*)&vtb[((size_t)bh * 64 + d) * 928 + kk] = v;
        }
    }
}

// ---------------------------------------------------------------------------
// attn v4: barrier-free QK/PV loops, bf16 direct-from-global fragments.
// Block = (b,h) x 32 q-rows, 4 waves; wave w owns k/d slice w*16..+15.
// LDS: only sc[32][936] bf16 (scores -> P).
// ---------------------------------------------------------------------------
__global__ __launch_bounds__(256) void attn_kernel(
    const short* __restrict__ qkvb, const short* __restrict__ vtb,
    const short* __restrict__ bgb, short* __restrict__ opb) {
    __shared__ short sc[32 * 936];
    const int t = threadIdx.x;
    const int w = t >> 6, lane = t & 63;
    const int c = lane & 15, g = lane >> 4;
    const int bh = blockIdx.y, b = bh >> 3, h = bh & 7;
    const int q0 = blockIdx.x * 32;
    const size_t rowb = (size_t)b * S_LEN;

    // Q fragments (held in regs for the whole kernel)
    short8 qa[2][2];
    #pragma unroll
    for (int qt = 0; qt < 2; ++qt) {
        int q = q0 + qt * 16 + c; if (q > S_LEN - 1) q = S_LEN - 1;
        const short* qp = qkvb + (rowb + q) * 1536 + h * 64;
        qa[qt][0] = *(const short8*)(qp + g * 8);
        qa[qt][1] = *(const short8*)(qp + 32 + g * 8);
    }
    const int n = w * 16 + c;

    // ---- QK^T (no barriers) ----
    for (int kt0 = 0; kt0 < 960; kt0 += 64) {
        int k = kt0 + n;
        int kc = k > S_LEN - 1 ? S_LEN - 1 : k;
        const short* kp = qkvb + (rowb + kc) * 1536 + 512 + h * 64;
        short8 kb0 = *(const short8*)(kp + g * 8);
        short8 kb1 = *(const short8*)(kp + 32 + g * 8);
        f32x4 s0 = {0.f, 0.f, 0.f, 0.f}, s1 = {0.f, 0.f, 0.f, 0.f};
        s0 = MFMA16(qa[0][0], kb0, s0, 0, 0, 0);
        s0 = MFMA16(qa[0][1], kb1, s0, 0, 0, 0);
        s1 = MFMA16(qa[1][0], kb0, s1, 0, 0, 0);
        s1 = MFMA16(qa[1][1], kb1, s1, 0, 0, 0);
        if (k < 928) {
            #pragma unroll
            for (int j = 0; j < 4; ++j) {
                sc[(g * 4 + j) * 936 + k]      = f2bf(s0[j] * 0.125f);
                sc[(16 + g * 4 + j) * 936 + k] = f2bf(s1[j] * 0.125f);
            }
        }
    }
    __syncthreads();

    // ---- softmax + bias (wave w owns rows w*8..w*8+7; 116 short8 chunks) ----
    #pragma unroll
    for (int rr = 0; rr < 8; ++rr) {
        int r = w * 8 + rr;
        int q = q0 + r;
        short8* rowp = (short8*)&sc[r * 936];
        bool has1 = lane < 52;
        if (q < S_LEN) {
            const short8* brow = (const short8*)(bgb + ((size_t)h * S_LEN + q) * 928);
            short8 c0 = rowp[lane], b0 = brow[lane];
            short8 c1 = c0, b1 = b0;
            if (has1) { c1 = rowp[64 + lane]; b1 = brow[64 + lane]; }
            float v0[8], v1[8];
            #pragma unroll
            for (int i = 0; i < 8; ++i) {
                v0[i] = bf2f(c0[i]) + bf2f(b0[i]);
                v1[i] = has1 ? (bf2f(c1[i]) + bf2f(b1[i])) : -1e30f;
            }
            float m = -1e30f;
            #pragma unroll
            for (int i = 0; i < 8; ++i) m = fmaxf(m, fmaxf(v0[i], v1[i]));
            #pragma unroll
            for (int off = 32; off >= 1; off >>= 1) m = fmaxf(m, __shfl_xor(m, off));
            float ssum = 0.f;
            #pragma unroll
            for (int i = 0; i < 8; ++i) {
                v0[i] = __expf(v0[i] - m); ssum += v0[i];
                v1[i] = __expf(v1[i] - m); ssum += v1[i];
            }
            #pragma unroll
            for (int off = 32; off >= 1; off >>= 1) ssum += __shfl_xor(ssum, off);
            float inv = 1.f / ssum;
            short8 p0, p1;
            #pragma unroll
            for (int i = 0; i < 8; ++i) {
                p0[i] = f2bf(v0[i] * inv);
                p1[i] = f2bf(v1[i] * inv);
            }
            rowp[lane] = p0;
            if (has1) rowp[64 + lane] = p1;
        } else {
            short8 z = {0, 0, 0, 0, 0, 0, 0, 0};
            rowp[lane] = z;
            if (has1) rowp[64 + lane] = z;
        }
    }
    __syncthreads();

    // ---- PV (no barriers) ----
    f32x4 o0 = {0.f, 0.f, 0.f, 0.f}, o1 = {0.f, 0.f, 0.f, 0.f};
    const short* vp = vtb + ((size_t)bh * 64 + n) * 928 + g * 8;
    for (int k0 = 0; k0 < 928; k0 += 32) {
        short8 vb = *(const short8*)(vp + k0);
        short8 p0 = *(const short8*)&sc[c * 936 + k0 + g * 8];
        short8 p1 = *(const short8*)&sc[(16 + c) * 936 + k0 + g * 8];
        o0 = MFMA16(p0, vb, o0, 0, 0, 0);
        o1 = MFMA16(p1, vb, o1, 0, 0, 0);
    }
    int d = h * 64 + n;
    #pragma unroll
    for (int j = 0; j < 4; ++j) {
        int q = q0 + g * 4 + j;
        if (q < S_LEN) opb[(rowb + q) * 512 + d] = f2bf(o0[j]);
        q += 16;
        if (q < S_LEN) opb[(rowb + q) * 512 + d] = f2bf(o1[j]);
    }
}

// ---------------------------------------------------------------------------
// LN: out = LN(src(bf16) + res) * g + b ; res f32 or bf16; out bf16 or f32
// ---------------------------------------------------------------------------
__global__ __launch_bounds__(256) void ln_kernel(
    const short* __restrict__ src, const float* __restrict__ resf,
    const short* __restrict__ resb, const float* __restrict__ g,
    const float* __restrict__ bb, short* __restrict__ outb,
    float* __restrict__ outf) {
    int row = blockIdx.x * 4 + (threadIdx.x >> 6);
    int lane = threadIdx.x & 63;
    int base = row * 512 + lane * 8;
    short8 s8 = *(const short8*)&src[base];
    float v[8];
    float tot = 0.f;
    if (resf) {
        float4 r0 = *(const float4*)&resf[base];
        float4 r1 = *(const float4*)&resf[base + 4];
        float rr[8] = {r0.x, r0.y, r0.z, r0.w, r1.x, r1.y, r1.z, r1.w};
        #pragma unroll
        for (int i = 0; i < 8; ++i) { v[i] = bf2f(s8[i]) + rr[i]; tot += v[i]; }
    } else {
        short8 r8 = *(const short8*)&resb[base];
        #pragma unroll
        for (int i = 0; i < 8; ++i) { v[i] = bf2f(s8[i]) + bf2f(r8[i]); tot += v[i]; }
    }
    #pragma unroll
    for (int off = 32; off >= 1; off >>= 1) tot += __shfl_xor(tot, off);
    float mean = tot * (1.f / 512.f);
    float var = 0.f;
    #pragma unroll
    for (int i = 0; i < 8; ++i) { v[i] -= mean; var += v[i] * v[i]; }
    #pragma unroll
    for (int off = 32; off >= 1; off >>= 1) var += __shfl_xor(var, off);
    float rstd = rsqrtf(var * (1.f / 512.f) + 1e-5f);
    int cb = lane * 8;
    if (outb) {
        short8 o;
        #pragma unroll
        for (int i = 0; i < 8; ++i) o[i] = f2bf(v[i] * rstd * g[cb + i] + bb[cb + i]);
        *(short8*)&outb[base] = o;
    } else {
        #pragma unroll
        for (int i = 0; i < 8; ++i) outf[base + i] = v[i] * rstd * g[cb + i] + bb[cb + i];
    }
}

__global__ void mean_part_kernel(const short* __restrict__ ao, float* __restrict__ partial) {
    int b = blockIdx.x, chunk = blockIdx.y, t = threadIdx.x;
    int s0 = chunk * 100;
    for (int c = t; c < 512; c += 256) {
        float s = 0.f;
        for (int i = 0; i < 100; ++i)
            s += bf2f(ao[((size_t)(b * S_LEN + s0 + i)) * 512 + c]);
        partial[((size_t)(b * 9 + chunk)) * 512 + c] = s;
    }
}

__global__ void mean_final_kernel(const float* __restrict__ partial, float* __restrict__ gfeat) {
    int idx = blockIdx.x * 256 + threadIdx.x;
    if (idx >= 16 * 512) return;
    int b = idx / 512, c = idx % 512;
    float s = 0.f;
    for (int i = 0; i < 9; ++i) s += partial[((size_t)(b * 9 + i)) * 512 + c];
    gfeat[idx] = s * (1.0f / 900.0f);
}

__global__ void heads_kernel(const float* __restrict__ gfeat,
    const float* __restrict__ rot_w, const float* __restrict__ rot_b,
    const float* __restrict__ refl_w, const float* __restrict__ refl_b,
    const float* __restrict__ trans_w, const float* __restrict__ trans_b,
    const float* __restrict__ scale_w, const float* __restrict__ scale_b,
    float* __restrict__ dout, float* __restrict__ tp_ws) {
    int b = blockIdx.x, t = threadIdx.x;
    __shared__ float hv[17], tpl[17];
    if (t < 17) {
        const float* wrow; float bb;
        if (t < 4)       { wrow = rot_w + t * 512;          bb = rot_b[t]; }
        else if (t < 12) { wrow = refl_w + (t - 4) * 512;   bb = refl_b[t - 4]; }
        else if (t < 14) { wrow = trans_w + (t - 12) * 512; bb = trans_b[t - 12]; }
        else             { wrow = scale_w + (t - 14) * 512; bb = scale_b[t - 14]; }
        const float* gf = gfeat + b * 512;
        float s = bb;
        for (int i = 0; i < 512; ++i) s += gf[i] * wrow[i];
        if (t == 12 || t == 13) s = tanhf(s);
        hv[t] = s;
    }
    __syncthreads();
    if (t == 0) {
        for (int gidx = 0; gidx < 3; ++gidx) {
            int o = (gidx == 0) ? 0 : (gidx == 1) ? 4 : 14;
            int nn = (gidx == 0) ? 4 : (gidx == 1) ? 8 : 3;
            float m = hv[o];
            for (int i = 1; i < nn; ++i) m = fmaxf(m, hv[o + i]);
            float sum = 0.f;
            for (int i = 0; i < nn; ++i) { float e = expf(hv[o + i] - m); tpl[o + i] = e; sum += e; }
            float inv = 1.f / sum;
            for (int i = 0; i < nn; ++i) tpl[o + i] *= inv;
        }
        tpl[12] = hv[12];
        tpl[13] = hv[13];
    }
    __syncthreads();
    if (t < 4)  dout[OFF_ROT + b * 4 + t] = hv[t];
    if (t < 8)  dout[OFF_REFL + b * 8 + t] = hv[4 + t];
    if (t < 2)  dout[OFF_TRANS + b * 2 + t] = hv[12 + t];
    if (t < 3)  dout[OFF_SCAL + b * 3 + t] = hv[14 + t];
    if (t < 17) { dout[OFF_TP + b * 17 + t] = tpl[t]; tp_ws[b * 17 + t] = tpl[t]; }
}

// ti[M,544] bf16: cols<512 = attn_out, 512..528 = tp, 529..543 = 0
__global__ void ti_kernel(const short* __restrict__ ao, const float* __restrict__ tp,
                          short* __restrict__ tib) {
    int idx = blockIdx.x * 256 + threadIdx.x;
    if (idx >= MTOT * 68) return;
    int r = idx / 68, c8 = (idx % 68) * 8;
    short8 v;
    if (c8 < 512) {
        v = *(const short8*)&ao[(size_t)r * 512 + c8];
    } else {
        int b = r / S_LEN;
        #pragma unroll
        for (int i = 0; i < 8; ++i) {
            int cc = c8 + i;
            v[i] = (cc < 529) ? f2bf(tp[b * 17 + (cc - 512)]) : (short)0;
        }
    }
    *(short8*)&tib[(size_t)r * 544 + c8] = v;
}

// ---------------------------------------------------------------------------
extern "C" void kernel_launch(void* const* d_in, const int* in_sizes, int n_in,
                              void* d_out, int out_size, void* d_ws, size_t ws_size,
                              hipStream_t stream) {
    const float* x       = (const float*)d_in[0];
    const float* wq      = (const float*)d_in[1];  const float* bq      = (const float*)d_in[2];
    const float* wk      = (const float*)d_in[3];  const float* bk      = (const float*)d_in[4];
    const float* wv      = (const float*)d_in[5];  const float* bv      = (const float*)d_in[6];
    const float* wo      = (const float*)d_in[7];  const float* bo      = (const float*)d_in[8];
    const float* ln_a_g  = (const float*)d_in[9];  const float* ln_a_b  = (const float*)d_in[10];
    const float* dist_e  = (const float*)d_in[11]; const float* dir_e   = (const float*)d_in[12];
    const float* rot_w   = (const float*)d_in[13]; const float* rot_b   = (const float*)d_in[14];
    const float* refl_w  = (const float*)d_in[15]; const float* refl_b  = (const float*)d_in[16];
    const float* trans_w = (const float*)d_in[17]; const float* trans_b = (const float*)d_in[18];
    const float* scale_w = (const float*)d_in[19]; const float* scale_b = (const float*)d_in[20];
    const float* tn1_w   = (const float*)d_in[21]; const float* tn1_b   = (const float*)d_in[22];
    const float* tn2_w   = (const float*)d_in[23]; const float* tn2_b   = (const float*)d_in[24];
    const float* tn3_w   = (const float*)d_in[25]; const float* tn3_b   = (const float*)d_in[26];
    const float* ff1_w   = (const float*)d_in[27]; const float* ff1_b   = (const float*)d_in[28];
    const float* ff2_w   = (const float*)d_in[29]; const float* ff2_b   = (const float*)d_in[30];
    const float* ln2_g   = (const float*)d_in[31]; const float* ln2_b   = (const float*)d_in[32];
    float* out = (float*)d_out;
    float* ws  = (float*)d_ws;

    // ws layout (f32 offsets), lifetime-overlapped; total ~203 MB
    short* wreg   = (short*)(ws + 0);            // 4,489,216 shorts
    float* bcat   = ws + 2250000;                // 1536 f
    short* xb     = (short*)(ws + 2260000);      // [M,512]
    short* qkvb   = (short*)(ws + 6000000);      // [M,1536]
    short* h1b    = (short*)(ws + 6000000);      // reuse (qkvb dead)
    short* h2b    = (short*)(ws + 13400000);
    short* vtb    = (short*)(ws + 17100000);     // [128][64][928]
    short* bgb    = (short*)(ws + 21000000);     // [8][900][928]
    short* t1b    = (short*)(ws + 24400000);     // wo out
    short* ffhb   = (short*)(ws + 17100000);     // reuse vtb/bgb/t1b (dead)
    short* opb    = (short*)(ws + 31900000);     // attn out
    short* aob    = (short*)(ws + 35600000);     // attn_out (LN1 out)
    short* tib    = (short*)(ws + 39300000);     // [M,544]
    short* geob   = (short*)(ws + 43300000);
    short* ffob   = (short*)(ws + 47000000);
    float* gfeat  = ws + 50700000;
    float* partial= ws + 50710000;
    float* tpbuf  = ws + 50790000;

    short* wcatb = wreg;
    short* wob   = wreg + 786432;
    short* tn1wb = wreg + 1048576;
    short* tn2wb = wreg + 1605632;
    short* tn3wb = wreg + 2129920;
    short* ff1wb = wreg + 2392064;
    short* ff2wb = wreg + 3440640;

    dim3 blk(256);
    prep_kernel<<<46342, blk, 0, stream>>>(wq, wk, wv, wo, tn1_w, tn2_w, tn3_w, ff1_w, ff2_w,
                                           bq, bk, bv, x, wreg, bcat, xb);
    geo_bias_kernel<<<3263, blk, 0, stream>>>(dist_e, dir_e, bgb);
    gemm_kernel<<<dim3(12, 113), blk, 0, stream>>>(xb, wcatb, bcat, nullptr, qkvb, MTOT, 1536, 512, 0);
    vt_kernel<<<dim3(15, 128), blk, 0, stream>>>(qkvb, vtb);
    attn_kernel<<<dim3(29, 128), blk, 0, stream>>>(qkvb, vtb, bgb, opb);
    gemm_kernel<<<dim3(4, 113), blk, 0, stream>>>(opb, wob, bo, nullptr, t1b, MTOT, 512, 512, 0);
    ln_kernel<<<3600, blk, 0, stream>>>(t1b, x, nullptr, ln_a_g, ln_a_b, aob, nullptr);
    mean_part_kernel<<<dim3(16, 9), blk, 0, stream>>>(aob, partial);
    mean_final_kernel<<<32, blk, 0, stream>>>(partial, gfeat);
    heads_kernel<<<16, 64, 0, stream>>>(gfeat, rot_w, rot_b, refl_w, refl_b,
                                        trans_w, trans_b, scale_w, scale_b, out, tpbuf);
    ti_kernel<<<3825, blk, 0, stream>>>(aob, tpbuf, tib);
    gemm_kernel<<<dim3(8, 113), blk, 0, stream>>>(tib, tn1wb, tn1_b, nullptr, h1b, MTOT, 1024, 544, 1);
    gemm_kernel<<<dim3(4, 113), blk, 0, stream>>>(h1b, tn2wb, tn2_b, nullptr, h2b, MTOT, 512, 1024, 1);
    gemm_kernel<<<dim3(4, 113), blk, 0, stream>>>(h2b, tn3wb, tn3_b, aob, geob, MTOT, 512, 512, 2);
    gemm_kernel<<<dim3(16, 113), blk, 0, stream>>>(geob, ff1wb, ff1_b, nullptr, ffhb, MTOT, 2048, 512, 1);
    gemm_kernel<<<dim3(4, 113), blk, 0, stream>>>(ffhb, ff2wb, ff2_b, nullptr, ffob, MTOT, 512, 2048, 0);
    ln_kernel<<<3600, blk, 0, stream>>>(ffob, nullptr, geob, ln2_g, ln2_b, nullptr, out);
}